// Round 1
// baseline (732.728 us; speedup 1.0000x reference)
//
#include <hip/hip_runtime.h>
#include <math.h>

#define NANCH 76725
#define NCLS 80
#define NIMG 4
#define PREK 512
#define MAXDET 100
#define CONF_THRF 0.05f
#define IOU_THRF 0.5f

__device__ __forceinline__ unsigned mono_key(float s) {
    unsigned b = __float_as_uint(s);
    return (b & 0x80000000u) ? ~b : (b | 0x80000000u);
}
__device__ __forceinline__ float mono_val(unsigned k) {
    return (k & 0x80000000u) ? __uint_as_float(k ^ 0x80000000u) : __uint_as_float(~k);
}
// Correctly-rounded-to-f32 sigmoid via double; score values feed top_k tie-breaks.
__device__ __forceinline__ float sigmoid_f(float x) {
    return (float)(1.0 / (1.0 + exp(-(double)x)));
}

// RetinaNet anchors, levels 3..7, 640x640, xywh. Replicates reference float32 math.
__device__ void anchor_at(int idx, float& ax, float& ay, float& aw, float& ah) {
    int l, li = idx;
    if (idx < 57600)      { l = 0; }
    else if (idx < 72000) { l = 1; li = idx - 57600; }
    else if (idx < 75600) { l = 2; li = idx - 72000; }
    else if (idx < 76500) { l = 3; li = idx - 75600; }
    else                  { l = 4; li = idx - 76500; }
    int stride = 8 << l;          // 8,16,32,64,128
    int fsz = 640 >> (3 + l);     // 80,40,20,10,5
    int cell = li / 9, a = li - cell * 9;
    int cyi = cell / fsz, cxi = cell - cyi * fsz;
    float fst = (float)stride;
    ax = ((float)cxi + 0.5f) * fst;
    ay = ((float)cyi + 0.5f) * fst;
    float side = (float)(stride * 4);     // 2^(l+5): 32..512
    float area = side * side;
    int ri = a / 3, si = a - ri * 3;
    float ratio = (ri == 0) ? 0.5f : ((ri == 1) ? 1.0f : 2.0f);
    float scl = (si == 0) ? 1.0f
              : ((si == 1) ? 1.25992104989487316476721f     // 2^(1/3)
                           : 1.58740105196819947475170564f); // 2^(2/3)
    float h = sqrtf(area / ratio);
    float w = area / h;
    aw = scl * w;
    ah = scl * h;
}

// ---------------- Kernel 1: class-major sort keys (transpose + sigmoid) -------
__global__ __launch_bounds__(256) void keys_kernel(const float* __restrict__ pred,
                                                   unsigned* __restrict__ keys) {
    __shared__ float tile[64][85];  // +1 pad breaks bank conflicts on transposed read
    int b = blockIdx.y;
    int i0 = blockIdx.x * 64;
    int tid = threadIdx.x;
    int nrow = NANCH - i0; if (nrow > 64) nrow = 64;
    // coalesced: address = (b*NANCH + i0)*84 + idx
    for (int idx = tid; idx < 64 * 84; idx += 256) {
        int r = idx / 84, col = idx - r * 84;
        if (r < nrow) tile[r][col] = pred[((size_t)b * NANCH + i0 + r) * 84 + col];
    }
    __syncthreads();
    for (int idx = tid; idx < NCLS * 64; idx += 256) {
        int c = idx >> 6, r = idx & 63;
        if (r < nrow) {
            unsigned mk = mono_key(sigmoid_f(tile[r][4 + c]));
            keys[((size_t)(b * NCLS + c)) * NANCH + (i0 + r)] = mk;
        }
    }
}

// parallel suffix (inclusive, from high index down) over 2048 u32 in LDS, 512 thr
__device__ __forceinline__ void suffix_scan_2048(unsigned* h, int tid) {
    for (unsigned off = 1; off < 2048; off <<= 1) {
        unsigned v[4];
#pragma unroll
        for (int q = 0; q < 4; q++) {
            unsigned t = (unsigned)tid + q * 512u;
            v[q] = (t + off < 2048u) ? h[t + off] : 0u;
        }
        __syncthreads();
#pragma unroll
        for (int q = 0; q < 4; q++) h[tid + q * 512] += v[q];
        __syncthreads();
    }
}

// ---------------- Kernel 2: per-(image,class) top-512 select + NMS + top-100 --
__global__ __launch_bounds__(512) void select_nms_kernel(
        const float* __restrict__ pred, const unsigned* __restrict__ keys,
        float* __restrict__ cls_scores, float* __restrict__ cls_boxes) {
    int bc = blockIdx.x;
    int b = bc / NCLS, c = bc - b * NCLS;
    int tid = threadIdx.x;
    const unsigned* kp = keys ? (keys + (size_t)bc * NANCH) : nullptr;
    const float* predc = pred + (size_t)b * NANCH * 84 + 4 + c;

    __shared__ unsigned hist[2048];
    __shared__ unsigned long long list[PREK];
    __shared__ unsigned eqlist[1024];
    __shared__ float sx1[PREK], sy1[PREK], sx2[PREK], sy2[PREK], sarea[PREK];
    __shared__ int skeep[PREK], svalid_s[PREK], spre[PREK];
    __shared__ unsigned sh_t, sh_above, s_cnt, s_eq;

    auto getkey = [&](int i) -> unsigned {
        if (kp) return kp[i];
        return mono_key(sigmoid_f(predc[(size_t)i * 84]));
    };

    // ---- level 0: top 11 bits ----
    for (int t = tid; t < 2048; t += 512) hist[t] = 0u;
    __syncthreads();
    for (int i = tid; i < NANCH; i += 512) atomicAdd(&hist[getkey(i) >> 21], 1u);
    __syncthreads();
    suffix_scan_2048(hist, tid);
    unsigned target = PREK;
#pragma unroll
    for (int q = 0; q < 4; q++) {
        int t = tid + q * 512;
        unsigned St = hist[t], St1 = (t < 2047) ? hist[t + 1] : 0u;
        if (St >= target && St1 < target) { sh_t = (unsigned)t; sh_above = St1; }
    }
    __syncthreads();
    unsigned t0 = sh_t, above = sh_above;
    __syncthreads();

    // ---- level 1: next 11 bits ----
    for (int t = tid; t < 2048; t += 512) hist[t] = 0u;
    __syncthreads();
    for (int i = tid; i < NANCH; i += 512) {
        unsigned k = getkey(i);
        if ((k >> 21) == t0) atomicAdd(&hist[(k >> 10) & 0x7FFu], 1u);
    }
    __syncthreads();
    suffix_scan_2048(hist, tid);
    target = PREK - above;
#pragma unroll
    for (int q = 0; q < 4; q++) {
        int t = tid + q * 512;
        unsigned St = hist[t], St1 = (t < 2047) ? hist[t + 1] : 0u;
        if (St >= target && St1 < target) { sh_t = (unsigned)t; sh_above = St1; }
    }
    __syncthreads();
    unsigned t1 = sh_t; above += sh_above;
    __syncthreads();

    // ---- level 2: low 10 bits ----
    for (int t = tid; t < 2048; t += 512) hist[t] = 0u;
    __syncthreads();
    unsigned pfx2 = (t0 << 11) | t1;
    for (int i = tid; i < NANCH; i += 512) {
        unsigned k = getkey(i);
        if ((k >> 10) == pfx2) atomicAdd(&hist[k & 0x3FFu], 1u);
    }
    __syncthreads();
    suffix_scan_2048(hist, tid);
    target = PREK - above;
#pragma unroll
    for (int q = 0; q < 4; q++) {
        int t = tid + q * 512;
        unsigned St = hist[t], St1 = (t < 2047) ? hist[t + 1] : 0u;
        if (St >= target && St1 < target) { sh_t = (unsigned)t; sh_above = St1; }
    }
    __syncthreads();
    unsigned t2 = sh_t; above += sh_above;
    unsigned B = (t0 << 21) | (t1 << 10) | t2;
    unsigned R = PREK - above;  // how many boundary-equal keys to take (by index asc)

    // ---- collect ----
    if (tid == 0) { s_cnt = 0u; s_eq = 0u; }
    __syncthreads();
    for (int i = tid; i < NANCH; i += 512) {
        unsigned k = getkey(i);
        if (k > B) {
            unsigned p = atomicAdd(&s_cnt, 1u);
            list[p] = ((unsigned long long)k << 32) | (unsigned long long)(0xFFFFFFFFu - (unsigned)i);
        } else if (k == B) {
            unsigned p = atomicAdd(&s_eq, 1u);
            if (p < 1024u) eqlist[p] = (unsigned)i;
        }
    }
    __syncthreads();
    unsigned eqn = s_eq < 1024u ? s_eq : 1024u;
    for (int t = tid; t < 1024; t += 512)
        if ((unsigned)t >= eqn) eqlist[t] = 0xFFFFFFFFu;
    __syncthreads();
    // bitonic ascending sort of boundary indices (top_k ties: smaller index first)
    for (unsigned k2 = 2; k2 <= 1024; k2 <<= 1)
        for (unsigned j = k2 >> 1; j > 0; j >>= 1) {
            for (int i = tid; i < 1024; i += 512) {
                unsigned ixj = (unsigned)i ^ j;
                if (ixj > (unsigned)i) {
                    unsigned a = eqlist[i], bb = eqlist[ixj];
                    bool asc = (((unsigned)i & k2) == 0u);
                    bool sw = asc ? (a > bb) : (a < bb);
                    if (sw) { eqlist[i] = bb; eqlist[ixj] = a; }
                }
            }
            __syncthreads();
        }
    for (unsigned t = tid; t < R; t += 512) {
        unsigned idxe = eqlist[t];
        list[above + t] = ((unsigned long long)B << 32) | (unsigned long long)(0xFFFFFFFFu - idxe);
    }
    __syncthreads();

    // ---- bitonic sort 512 composites descending (score desc, index asc) ----
    for (unsigned k2 = 2; k2 <= PREK; k2 <<= 1)
        for (unsigned j = k2 >> 1; j > 0; j >>= 1) {
            unsigned i = (unsigned)tid, ixj = i ^ j;
            if (ixj > i) {
                unsigned long long a = list[i], bb = list[ixj];
                bool desc = ((i & k2) == 0u);
                bool sw = desc ? (a < bb) : (a > bb);
                if (sw) { list[i] = bb; list[ixj] = a; }
            }
            __syncthreads();
        }

    // ---- decode boxes for the 512 candidates ----
    unsigned long long e = list[tid];
    unsigned key = (unsigned)(e >> 32);
    unsigned aidx = 0xFFFFFFFFu - (unsigned)(e & 0xFFFFFFFFull);
    float score = mono_val(key);
    const float* pp = pred + ((size_t)b * NANCH + aidx) * 84;
    float ax, ay, aw, ah;
    anchor_at((int)aidx, ax, ay, aw, ah);
    float bx = pp[0] * 0.1f, by = pp[1] * 0.1f, bw2 = pp[2] * 0.2f, bh2 = pp[3] * 0.2f;
    float cx = bx * aw + ax, cy = by * ah + ay;
    float w = (float)exp((double)bw2) * aw;
    float h = (float)exp((double)bh2) * ah;
    float x1 = cx - w * 0.5f, y1 = cy - h * 0.5f;
    float x2 = cx + w * 0.5f, y2 = cy + h * 0.5f;
    sx1[tid] = x1; sy1[tid] = y1; sx2[tid] = x2; sy2[tid] = y2;
    float area = (x2 - x1) * (y2 - y1);
    sarea[tid] = area;
    skeep[tid] = 1;
    svalid_s[tid] = (score > CONF_THRF) ? 1 : 0;
    __syncthreads();

    // ---- sequential NMS, exact reference semantics ----
    for (int i = 0; i < PREK; i++) {
        int act = skeep[i] & svalid_s[i];  // uniform
        if (act) {
            if (tid > i) {
                float xx1 = fmaxf(sx1[i], x1);
                float yy1 = fmaxf(sy1[i], y1);
                float xx2 = fminf(sx2[i], x2);
                float yy2 = fminf(sy2[i], y2);
                float ww = fmaxf(xx2 - xx1, 0.0f);
                float hh = fmaxf(yy2 - yy1, 0.0f);
                float inter = ww * hh;
                float uni = sarea[i] + area - inter;
                float iou = inter / fmaxf(uni, 1e-8f);
                if (iou > IOU_THRF) skeep[tid] = 0;
            }
        }
        __syncthreads();
    }

    // ---- compact kept (sorted order preserved) → per-class top-100 ----
    int kept = skeep[tid] & svalid_s[tid];
    spre[tid] = kept;
    __syncthreads();
    for (int off = 1; off < PREK; off <<= 1) {
        int v = (tid >= off) ? spre[tid - off] : 0;
        __syncthreads();
        spre[tid] += v;
        __syncthreads();
    }
    int rank = spre[tid] - kept;  // exclusive prefix

    float* cs = cls_scores + (size_t)bc * MAXDET;
    float* cb = cls_boxes + (size_t)bc * MAXDET * 4;
    for (int r = tid; r < MAXDET; r += 512) {
        cs[r] = -1.0f;
        cb[r * 4 + 0] = -1.0f; cb[r * 4 + 1] = -1.0f;
        cb[r * 4 + 2] = -1.0f; cb[r * 4 + 3] = -1.0f;
    }
    __syncthreads();
    if (kept && rank < MAXDET) {
        cs[rank] = score;
        cb[rank * 4 + 0] = cx; cb[rank * 4 + 1] = cy;
        cb[rank * 4 + 2] = w;  cb[rank * 4 + 3] = h;
    }
}

// ---------------- Kernel 3: per-image top-100 of 8000 + masking + count -------
__global__ __launch_bounds__(1024) void final_topk(const float* __restrict__ cls_scores,
                                                   const float* __restrict__ cls_boxes,
                                                   float* __restrict__ out) {
    int b = blockIdx.x;
    int tid = threadIdx.x;
    __shared__ unsigned khi[8192];
    __shared__ unsigned klo[8192];
    for (int i = tid; i < 8192; i += 1024) {
        if (i < NCLS * MAXDET) {
            float s = cls_scores[(size_t)b * NCLS * MAXDET + i];
            khi[i] = mono_key(s);
            klo[i] = 0xFFFFFFFFu - (unsigned)i;  // ties: smaller flat index first
        } else {
            khi[i] = 0u; klo[i] = 0u;
        }
    }
    __syncthreads();
    for (unsigned k = 2; k <= 8192; k <<= 1)
        for (unsigned j = k >> 1; j > 0; j >>= 1) {
            for (unsigned i = tid; i < 8192; i += 1024) {
                unsigned ixj = i ^ j;
                if (ixj > i) {
                    unsigned ahi = khi[i], alo = klo[i];
                    unsigned bhi = khi[ixj], blo = klo[ixj];
                    bool iless = (ahi < bhi) || (ahi == bhi && alo < blo);
                    bool igtr  = (bhi < ahi) || (ahi == bhi && blo < alo);
                    bool desc = ((i & k) == 0u);
                    if (desc ? iless : igtr) {
                        khi[i] = bhi; klo[i] = blo;
                        khi[ixj] = ahi; klo[ixj] = alo;
                    }
                }
            }
            __syncthreads();
        }

    bool v = false;
    if (tid < MAXDET) {
        unsigned mk = khi[tid];
        float s = mono_val(mk);
        unsigned fi = 0xFFFFFFFFu - klo[tid];
        v = (s >= CONF_THRF);
        float obx = -1.0f, oby = -1.0f, obw = -1.0f, obh = -1.0f;
        float ofs = -1.0f, ofc = -1.0f;
        if (v) {
            const float* bp = cls_boxes + ((size_t)b * NCLS * MAXDET + fi) * 4;
            obx = bp[0]; oby = bp[1]; obw = bp[2]; obh = bp[3];
            ofs = s;
            ofc = (float)(fi / MAXDET);
        }
        int o = b * MAXDET + tid;
        out[o * 4 + 0] = obx; out[o * 4 + 1] = oby;
        out[o * 4 + 2] = obw; out[o * 4 + 3] = obh;
        out[NIMG * MAXDET * 4 + o] = ofs;
        out[NIMG * MAXDET * 5 + o] = ofc;
    }
    __syncthreads();
    if (tid == 0) klo[0] = 0u;
    __syncthreads();
    if (tid < MAXDET && v) atomicAdd(&klo[0], 1u);
    __syncthreads();
    if (tid == 0) out[NIMG * MAXDET * 6 + b] = (float)klo[0];
}

extern "C" void kernel_launch(void* const* d_in, const int* in_sizes, int n_in,
                              void* d_out, int out_size, void* d_ws, size_t ws_size,
                              hipStream_t stream) {
    (void)in_sizes; (void)n_in; (void)out_size;
    const float* pred = (const float*)d_in[1];  // d_in[0] = images (only H=W=640 used)
    float* out = (float*)d_out;

    size_t keys_bytes = (size_t)NIMG * NCLS * NANCH * 4u;          // ~98.2 MB
    size_t cls_scores_bytes = (size_t)NIMG * NCLS * MAXDET * 4u;   // 128 KB
    size_t cls_boxes_bytes = cls_scores_bytes * 4u;                // 512 KB
    bool use_keys = ws_size >= keys_bytes + cls_scores_bytes + cls_boxes_bytes;

    char* base = (char*)d_ws;
    unsigned* keys = nullptr;
    float* cls_scores;
    float* cls_boxes;
    if (use_keys) {
        keys = (unsigned*)base;
        cls_scores = (float*)(base + keys_bytes);
        cls_boxes = (float*)(base + keys_bytes + cls_scores_bytes);
        dim3 g((NANCH + 63) / 64, NIMG);
        keys_kernel<<<g, 256, 0, stream>>>(pred, keys);
    } else {
        // fallback: recompute keys from pred on the fly (slower, strided reads)
        cls_scores = (float*)base;
        cls_boxes = (float*)(base + cls_scores_bytes);
    }
    select_nms_kernel<<<NIMG * NCLS, 512, 0, stream>>>(pred, keys, cls_scores, cls_boxes);
    final_topk<<<NIMG, 1024, 0, stream>>>(cls_scores, cls_boxes, out);
}

// Round 2
// 677.742 us; speedup vs baseline: 1.0811x; 1.0811x over previous
//
#include <hip/hip_runtime.h>
#include <math.h>

#define NANCH 76725
#define NCLS 80
#define NIMG 4
#define PREK 512
#define MAXDET 100
#define CONF_THRF 0.05f
#define IOU_THRF 0.5f
#define XCUT 2.2f            // logit cut: sigmoid(2.2)=0.90025; 512th-best per class ~0.92 (>>17 sigma margin)
#define LCAP 2048            // per-(image,class) candidate list capacity (expected ~1066 +/- 32)
#define F4_PER_IMG 1611225   // 76725*84/4
#define EL_PER_IMG 6444900   // 76725*84

__device__ __forceinline__ unsigned mono_key(float s) {
    unsigned b = __float_as_uint(s);
    return (b & 0x80000000u) ? ~b : (b | 0x80000000u);
}
__device__ __forceinline__ float mono_val(unsigned k) {
    return (k & 0x80000000u) ? __uint_as_float(k ^ 0x80000000u) : __uint_as_float(~k);
}
// Correctly-rounded-to-f32 sigmoid via double; matched XLA-CPU exactly in round 1 (absmax 0.0).
__device__ __forceinline__ float sigmoid_f(float x) {
    return (float)(1.0 / (1.0 + exp(-(double)x)));
}

// RetinaNet anchors, levels 3..7, 640x640, xywh. Replicates reference float32 math.
__device__ void anchor_at(int idx, float& ax, float& ay, float& aw, float& ah) {
    int l, li = idx;
    if (idx < 57600)      { l = 0; }
    else if (idx < 72000) { l = 1; li = idx - 57600; }
    else if (idx < 75600) { l = 2; li = idx - 72000; }
    else if (idx < 76500) { l = 3; li = idx - 75600; }
    else                  { l = 4; li = idx - 76500; }
    int stride = 8 << l;
    int fsz = 640 >> (3 + l);
    int cell = li / 9, a = li - cell * 9;
    int cyi = cell / fsz, cxi = cell - cyi * fsz;
    float fst = (float)stride;
    ax = ((float)cxi + 0.5f) * fst;
    ay = ((float)cyi + 0.5f) * fst;
    float side = (float)(stride * 4);
    float area = side * side;
    int ri = a / 3, si = a - ri * 3;
    float ratio = (ri == 0) ? 0.5f : ((ri == 1) ? 1.0f : 2.0f);
    float scl = (si == 0) ? 1.0f
              : ((si == 1) ? 1.25992104989487316476721f
                           : 1.58740105196819947475170564f);
    float h = sqrtf(area / ratio);
    float w = area / h;
    aw = scl * w;
    ah = scl * h;
}

__device__ __forceinline__ void emit_cand(int b, unsigned el, float x,
                                          unsigned long long* glist, unsigned* gcnt) {
    unsigned anchor = el / 84u;
    unsigned col = el - anchor * 84u;
    int c = (int)col - 4;
    unsigned key = mono_key(sigmoid_f(x));
    int bc = b * NCLS + c;
    unsigned pos = atomicAdd(&gcnt[bc], 1u);
    if (pos < LCAP)
        glist[(size_t)bc * LCAP + pos] =
            ((unsigned long long)key << 32) | (unsigned long long)(0xFFFFFFFFu - anchor);
}

// ---------------- Kernel 1: threshold-collect candidates (one coalesced pass) --
__global__ __launch_bounds__(256) void collect_kernel(const float* __restrict__ pred,
                                                      unsigned long long* __restrict__ glist,
                                                      unsigned* __restrict__ gcnt) {
    __shared__ unsigned pend[1024];
    __shared__ unsigned s_p;
    int b = blockIdx.y;
    int tid = threadIdx.x;
    unsigned base4 = (unsigned)blockIdx.x * 1280u;
    if (tid == 0) s_p = 0u;
    __syncthreads();
    const float4* p4 = (const float4*)(pred + (size_t)b * EL_PER_IMG);
#pragma unroll
    for (int k = 0; k < 5; k++) {
        unsigned f = base4 + (unsigned)(k * 256 + tid);
        if (f < (unsigned)F4_PER_IMG) {
            unsigned colb = f % 21u;         // 0 => box-delta columns 0..3, skip test
            float4 v = p4[f];
            if (colb != 0u) {
                if (v.x >= XCUT || v.y >= XCUT || v.z >= XCUT || v.w >= XCUT) {
                    float xs0 = v.x, xs1 = v.y, xs2 = v.z, xs3 = v.w;
#pragma unroll
                    for (int j = 0; j < 4; j++) {
                        float x = (j == 0) ? xs0 : (j == 1) ? xs1 : (j == 2) ? xs2 : xs3;
                        if (x >= XCUT) {
                            unsigned pos = atomicAdd(&s_p, 1u);
                            unsigned el = f * 4u + (unsigned)j;
                            if (pos < 1024u) pend[pos] = el;
                            else emit_cand(b, el, x, glist, gcnt);  // overflow: slow exact path
                        }
                    }
                }
            }
        }
    }
    __syncthreads();
    // dense second phase: f64 sigmoid only on compacted hits (~71/block)
    unsigned np = s_p; if (np > 1024u) np = 1024u;
    for (unsigned i = (unsigned)tid; i < np; i += 256u) {
        unsigned el = pend[i];
        float x = pred[(size_t)b * EL_PER_IMG + el];
        emit_cand(b, el, x, glist, gcnt);
    }
}

// parallel suffix (inclusive, from high index down) over 2048 u32 in LDS, 512 thr
__device__ __forceinline__ void suffix_scan_2048(unsigned* h, int tid) {
    for (unsigned off = 1; off < 2048; off <<= 1) {
        unsigned v[4];
#pragma unroll
        for (int q = 0; q < 4; q++) {
            unsigned t = (unsigned)tid + q * 512u;
            v[q] = (t + off < 2048u) ? h[t + off] : 0u;
        }
        __syncthreads();
#pragma unroll
        for (int q = 0; q < 4; q++) h[tid + q * 512] += v[q];
        __syncthreads();
    }
}

// ---------------- Kernel 2: sort candidates + validity proof + bitmask NMS ----
__global__ __launch_bounds__(512) void select_nms_kernel(
        const float* __restrict__ pred, const unsigned long long* __restrict__ glist,
        const unsigned* __restrict__ gcnt,
        float* __restrict__ cls_scores, float* __restrict__ cls_boxes) {
    int bc = blockIdx.x;
    int b = bc / NCLS, c = bc - b * NCLS;
    int tid = threadIdx.x;

    __shared__ unsigned long long clist[2048];        // 16 KB: candidates; [0:512) = final sorted
    __shared__ unsigned rowb[512 * 17];               // 34.8 KB: NMS bit rows (17-stride kills bank conflicts)
                                                      //           fallback overlays hist[2048]+eqlist[1024]
    __shared__ float4 sbox[PREK];                     // 8 KB x1,y1,x2,y2
    __shared__ float sarea[PREK];                     // 2 KB
    __shared__ int svalid[PREK];                      // 2 KB
    __shared__ unsigned keepw[16];
    __shared__ unsigned wsum[8];
    __shared__ unsigned sh_t, sh_above, s_cnt, s_eq;

    const unsigned KCUT = mono_key(sigmoid_f(XCUT));
    unsigned cnt = gcnt[bc];

    for (int i = tid; i < 2048; i += 512)
        clist[i] = (i < (int)cnt) ? glist[(size_t)bc * LCAP + i] : 0ull;
    __syncthreads();

    bool fast = (cnt >= PREK && cnt <= LCAP);
    if (fast) {
        // bitonic sort 2048 u64 descending (key desc, index asc via ~idx in low32)
        for (unsigned kk = 2; kk <= 2048; kk <<= 1)
            for (unsigned j = kk >> 1; j > 0; j >>= 1) {
#pragma unroll
                for (int q = 0; q < 4; q++) {
                    unsigned i = (unsigned)tid + q * 512u;
                    unsigned ixj = i ^ j;
                    if (ixj > i) {
                        unsigned long long a = clist[i], bb = clist[ixj];
                        bool desc = ((i & kk) == 0u);
                        if (desc ? (a < bb) : (a > bb)) { clist[i] = bb; clist[ixj] = a; }
                    }
                }
                __syncthreads();
            }
        // proof: all uncollected keys are <= KCUT; strict > means top-512 is exact
        unsigned key511 = (unsigned)(clist[511] >> 32);
        fast = key511 > KCUT;
    }

    if (!fast) {
        // exact 3-level radix-select fallback (recompute keys, strided). Never taken
        // on the bench input; correctness net for arbitrary inputs.
        unsigned* hist = (unsigned*)rowb;
        unsigned* eqlist = hist + 2048;
        const float* predc = pred + (size_t)b * NANCH * 84 + 4 + c;
        auto getkey = [&](int i) -> unsigned {
            return mono_key(sigmoid_f(predc[(size_t)i * 84]));
        };
        for (int t = tid; t < 2048; t += 512) hist[t] = 0u;
        __syncthreads();
        for (int i = tid; i < NANCH; i += 512) atomicAdd(&hist[getkey(i) >> 21], 1u);
        __syncthreads();
        suffix_scan_2048(hist, tid);
        unsigned target = PREK;
#pragma unroll
        for (int q = 0; q < 4; q++) {
            int t = tid + q * 512;
            unsigned St = hist[t], St1 = (t < 2047) ? hist[t + 1] : 0u;
            if (St >= target && St1 < target) { sh_t = (unsigned)t; sh_above = St1; }
        }
        __syncthreads();
        unsigned t0 = sh_t, above = sh_above;
        __syncthreads();
        for (int t = tid; t < 2048; t += 512) hist[t] = 0u;
        __syncthreads();
        for (int i = tid; i < NANCH; i += 512) {
            unsigned k = getkey(i);
            if ((k >> 21) == t0) atomicAdd(&hist[(k >> 10) & 0x7FFu], 1u);
        }
        __syncthreads();
        suffix_scan_2048(hist, tid);
        target = PREK - above;
#pragma unroll
        for (int q = 0; q < 4; q++) {
            int t = tid + q * 512;
            unsigned St = hist[t], St1 = (t < 2047) ? hist[t + 1] : 0u;
            if (St >= target && St1 < target) { sh_t = (unsigned)t; sh_above = St1; }
        }
        __syncthreads();
        unsigned t1 = sh_t; above += sh_above;
        __syncthreads();
        for (int t = tid; t < 2048; t += 512) hist[t] = 0u;
        __syncthreads();
        unsigned pfx2 = (t0 << 11) | t1;
        for (int i = tid; i < NANCH; i += 512) {
            unsigned k = getkey(i);
            if ((k >> 10) == pfx2) atomicAdd(&hist[k & 0x3FFu], 1u);
        }
        __syncthreads();
        suffix_scan_2048(hist, tid);
        target = PREK - above;
#pragma unroll
        for (int q = 0; q < 4; q++) {
            int t = tid + q * 512;
            unsigned St = hist[t], St1 = (t < 2047) ? hist[t + 1] : 0u;
            if (St >= target && St1 < target) { sh_t = (unsigned)t; sh_above = St1; }
        }
        __syncthreads();
        unsigned t2 = sh_t; above += sh_above;
        unsigned B = (t0 << 21) | (t1 << 10) | t2;
        unsigned R = PREK - above;
        if (tid == 0) { s_cnt = 0u; s_eq = 0u; }
        __syncthreads();
        for (int i = tid; i < NANCH; i += 512) {
            unsigned k = getkey(i);
            if (k > B) {
                unsigned p = atomicAdd(&s_cnt, 1u);
                clist[p] = ((unsigned long long)k << 32) | (unsigned long long)(0xFFFFFFFFu - (unsigned)i);
            } else if (k == B) {
                unsigned p = atomicAdd(&s_eq, 1u);
                if (p < 1024u) eqlist[p] = (unsigned)i;
            }
        }
        __syncthreads();
        unsigned eqn = s_eq < 1024u ? s_eq : 1024u;
        for (int t = tid; t < 1024; t += 512)
            if ((unsigned)t >= eqn) eqlist[t] = 0xFFFFFFFFu;
        __syncthreads();
        for (unsigned k2 = 2; k2 <= 1024; k2 <<= 1)
            for (unsigned j = k2 >> 1; j > 0; j >>= 1) {
                for (int i = tid; i < 1024; i += 512) {
                    unsigned ixj = (unsigned)i ^ j;
                    if (ixj > (unsigned)i) {
                        unsigned a = eqlist[i], bb = eqlist[ixj];
                        bool asc = (((unsigned)i & k2) == 0u);
                        bool sw = asc ? (a > bb) : (a < bb);
                        if (sw) { eqlist[i] = bb; eqlist[ixj] = a; }
                    }
                }
                __syncthreads();
            }
        for (unsigned t = tid; t < R; t += 512) {
            unsigned idxe = eqlist[t];
            clist[above + t] = ((unsigned long long)B << 32) | (unsigned long long)(0xFFFFFFFFu - idxe);
        }
        __syncthreads();
        for (unsigned k2 = 2; k2 <= PREK; k2 <<= 1)
            for (unsigned j = k2 >> 1; j > 0; j >>= 1) {
                unsigned i = (unsigned)tid, ixj = i ^ j;
                if (ixj > i) {
                    unsigned long long a = clist[i], bb = clist[ixj];
                    bool desc = ((i & k2) == 0u);
                    bool sw = desc ? (a < bb) : (a > bb);
                    if (sw) { clist[i] = bb; clist[ixj] = a; }
                }
                __syncthreads();
            }
    }
    __syncthreads();

    // ---- decode the 512 sorted candidates ----
    unsigned long long e = clist[tid];
    unsigned key = (unsigned)(e >> 32);
    unsigned aidx = 0xFFFFFFFFu - (unsigned)(e & 0xFFFFFFFFull);
    float score = mono_val(key);
    const float4 pv = *(const float4*)(pred + ((size_t)b * NANCH + aidx) * 84);
    float ax, ay, aw, ah;
    anchor_at((int)aidx, ax, ay, aw, ah);
    float bx = pv.x * 0.1f, by = pv.y * 0.1f, bw2 = pv.z * 0.2f, bh2 = pv.w * 0.2f;
    float cx = bx * aw + ax, cy = by * ah + ay;
    float w = (float)exp((double)bw2) * aw;
    float h = (float)exp((double)bh2) * ah;
    float x1 = cx - w * 0.5f, y1 = cy - h * 0.5f;
    float x2 = cx + w * 0.5f, y2 = cy + h * 0.5f;
    float area = (x2 - x1) * (y2 - y1);
    sbox[tid] = make_float4(x1, y1, x2, y2);
    sarea[tid] = area;
    int validr = (score > CONF_THRF) ? 1 : 0;
    svalid[tid] = validr;
    __syncthreads();

    // ---- build 512x512 suppression bit-matrix (triangular by wave) ----
    int w_ = tid >> 6;
#pragma unroll
    for (int t = 0; t < 8; t++) {
        if (t < w_) {
            rowb[tid * 17 + 2 * t] = 0u;
            rowb[tid * 17 + 2 * t + 1] = 0u;
        } else {
            unsigned m0 = 0u, m1 = 0u;
            for (int jj = 0; jj < 64; jj++) {
                int j = t * 64 + jj;
                float4 bj = sbox[j];                  // LDS broadcast (uniform j per wave)
                float aj = sarea[j];
                float xx1 = fmaxf(x1, bj.x);
                float yy1 = fmaxf(y1, bj.y);
                float xx2 = fminf(x2, bj.z);
                float yy2 = fminf(y2, bj.w);
                float ww = fmaxf(xx2 - xx1, 0.0f);
                float hh = fmaxf(yy2 - yy1, 0.0f);
                float inter = ww * hh;
                float uni = area + aj - inter;
                float iou = inter / fmaxf(uni, 1e-8f);   // exact reference arithmetic
                bool sup = (iou > IOU_THRF) && (j > tid) && validr;
                if (jj < 32) m0 |= sup ? (1u << jj) : 0u;
                else         m1 |= sup ? (1u << (jj - 32)) : 0u;
            }
            rowb[tid * 17 + 2 * t] = m0;
            rowb[tid * 17 + 2 * t + 1] = m1;
        }
    }
    __syncthreads();

    // ---- single-wave sequential resolve over the bitmask ----
    if (tid < 64) {
        int lane = tid;
        unsigned kw = (lane < 16) ? 0xFFFFFFFFu : 0u;
        for (int i = 0; i < PREK; i++) {
            unsigned wv = (unsigned)__shfl((int)kw, i >> 5);
            bool ki = (wv >> (i & 31)) & 1u;          // wave-uniform
            if (ki) kw &= ~rowb[i * 17 + (lane & 15)];
        }
        if (lane < 16) keepw[lane] = kw;
    }
    __syncthreads();

    // ---- ballot compaction -> per-class top-100 ----
    unsigned kbit = (keepw[tid >> 5] >> (tid & 31)) & 1u;
    int kept = (int)kbit & svalid[tid];
    unsigned long long bal = __ballot(kept != 0);
    int lane6 = tid & 63;
    if (lane6 == 0) wsum[w_] = (unsigned)__popcll(bal);
    __syncthreads();
    int rank = 0;
    for (int u = 0; u < w_; u++) rank += (int)wsum[u];
    rank += (int)__popcll(bal & ((1ull << lane6) - 1ull));

    float* cs = cls_scores + (size_t)bc * MAXDET;
    float* cb = cls_boxes + (size_t)bc * MAXDET * 4;
    for (int r = tid; r < MAXDET; r += 512) {
        cs[r] = -1.0f;
        cb[r * 4 + 0] = -1.0f; cb[r * 4 + 1] = -1.0f;
        cb[r * 4 + 2] = -1.0f; cb[r * 4 + 3] = -1.0f;
    }
    __syncthreads();
    if (kept && rank < MAXDET) {
        cs[rank] = score;
        cb[rank * 4 + 0] = cx; cb[rank * 4 + 1] = cy;
        cb[rank * 4 + 2] = w;  cb[rank * 4 + 3] = h;
    }
}

// ---------------- Kernel 3: per-image top-100 of 8000 + masking + count -------
__global__ __launch_bounds__(1024) void final_topk(const float* __restrict__ cls_scores,
                                                   const float* __restrict__ cls_boxes,
                                                   float* __restrict__ out) {
    int b = blockIdx.x;
    int tid = threadIdx.x;
    __shared__ unsigned long long arr[8192];          // 64 KB exactly
    for (int i = tid; i < 8192; i += 1024) {
        if (i < NCLS * MAXDET) {
            float s = cls_scores[(size_t)b * NCLS * MAXDET + i];
            arr[i] = ((unsigned long long)mono_key(s) << 32)
                   | (unsigned long long)(0xFFFFFFFFu - (unsigned)i);
        } else arr[i] = 0ull;
    }
    __syncthreads();
    for (unsigned k = 2; k <= 8192; k <<= 1)
        for (unsigned j = k >> 1; j > 0; j >>= 1) {
#pragma unroll
            for (int q = 0; q < 8; q++) {
                unsigned i = (unsigned)tid + (unsigned)q * 1024u;
                unsigned ixj = i ^ j;
                if (ixj > i) {
                    unsigned long long a = arr[i], bb = arr[ixj];
                    bool desc = ((i & k) == 0u);
                    if (desc ? (a < bb) : (a > bb)) { arr[i] = bb; arr[ixj] = a; }
                }
            }
            __syncthreads();
        }

    bool v = false;
    if (tid < MAXDET) {
        unsigned long long e = arr[tid];
        unsigned mk = (unsigned)(e >> 32);
        float s = mono_val(mk);
        unsigned fi = 0xFFFFFFFFu - (unsigned)(e & 0xFFFFFFFFull);
        v = (s >= CONF_THRF);
        float obx = -1.0f, oby = -1.0f, obw = -1.0f, obh = -1.0f;
        float ofs = -1.0f, ofc = -1.0f;
        if (v) {
            const float* bp = cls_boxes + ((size_t)b * NCLS * MAXDET + fi) * 4;
            obx = bp[0]; oby = bp[1]; obw = bp[2]; obh = bp[3];
            ofs = s;
            ofc = (float)(fi / MAXDET);
        }
        int o = b * MAXDET + tid;
        out[o * 4 + 0] = obx; out[o * 4 + 1] = oby;
        out[o * 4 + 2] = obw; out[o * 4 + 3] = obh;
        out[NIMG * MAXDET * 4 + o] = ofs;
        out[NIMG * MAXDET * 5 + o] = ofc;
    }
    __syncthreads();
    unsigned long long bal = __ballot(v);
    if ((tid & 63) == 0) arr[tid >> 6] = bal;
    __syncthreads();
    if (tid == 0) {
        int cnt2 = 0;
        for (int u = 0; u < 16; u++) cnt2 += (int)__popcll(arr[u]);
        out[NIMG * MAXDET * 6 + b] = (float)cnt2;
    }
}

extern "C" void kernel_launch(void* const* d_in, const int* in_sizes, int n_in,
                              void* d_out, int out_size, void* d_ws, size_t ws_size,
                              hipStream_t stream) {
    (void)in_sizes; (void)n_in; (void)out_size; (void)ws_size;
    const float* pred = (const float*)d_in[1];  // d_in[0] = images (only H=W=640 used)
    float* out = (float*)d_out;

    char* base = (char*)d_ws;
    unsigned long long* glist = (unsigned long long*)base;                 // 320*2048*8 = 5.24 MB
    size_t glist_bytes = (size_t)NIMG * NCLS * LCAP * 8u;
    unsigned* gcnt = (unsigned*)(base + glist_bytes);                      // 1280 B
    float* cls_scores = (float*)(base + glist_bytes + 2048);               // 128 KB
    float* cls_boxes  = cls_scores + (size_t)NIMG * NCLS * MAXDET;         // 512 KB

    hipMemsetAsync(gcnt, 0, (size_t)NIMG * NCLS * sizeof(unsigned), stream);
    collect_kernel<<<dim3(1259, NIMG), 256, 0, stream>>>(pred, glist, gcnt);
    select_nms_kernel<<<NIMG * NCLS, 512, 0, stream>>>(pred, glist, gcnt, cls_scores, cls_boxes);
    final_topk<<<NIMG, 1024, 0, stream>>>(cls_scores, cls_boxes, out);
}

// Round 3
// 432.035 us; speedup vs baseline: 1.6960x; 1.5687x over previous
//
#include <hip/hip_runtime.h>
#include <math.h>

#define NANCH 76725
#define NCLS 80
#define NIMG 4
#define PREK 512
#define MAXDET 100
#define CONF_THRF 0.05f
#define IOU_THRF 0.5f
#define XCUT 2.2f            // logit cut: sigmoid(2.2)=0.90025; 512th-best per class ~0.92
#define NSTRIPE 16           // per-class atomic striping (by blockIdx.x & 15)
#define SCAP 128             // capacity per (class,stripe) sub-list; expected ~67 +/- 8
#define F4_PER_IMG 1611225   // 76725*84/4
#define EL_PER_IMG 6444900   // 76725*84
#define NSUB (NIMG * NCLS * NSTRIPE)   // 5120 sub-lists

__device__ __forceinline__ unsigned mono_key(float s) {
    unsigned b = __float_as_uint(s);
    return (b & 0x80000000u) ? ~b : (b | 0x80000000u);
}
__device__ __forceinline__ float mono_val(unsigned k) {
    return (k & 0x80000000u) ? __uint_as_float(k ^ 0x80000000u) : __uint_as_float(~k);
}
// Correctly-rounded-to-f32 sigmoid via double; matched XLA exactly (absmax 0.0 r1/r2).
__device__ __forceinline__ float sigmoid_f(float x) {
    return (float)(1.0 / (1.0 + exp(-(double)x)));
}

// RetinaNet anchors, levels 3..7, 640x640, xywh. Replicates reference float32 math.
__device__ void anchor_at(int idx, float& ax, float& ay, float& aw, float& ah) {
    int l, li = idx;
    if (idx < 57600)      { l = 0; }
    else if (idx < 72000) { l = 1; li = idx - 57600; }
    else if (idx < 75600) { l = 2; li = idx - 72000; }
    else if (idx < 76500) { l = 3; li = idx - 75600; }
    else                  { l = 4; li = idx - 76500; }
    int stride = 8 << l;
    int fsz = 640 >> (3 + l);
    int cell = li / 9, a = li - cell * 9;
    int cyi = cell / fsz, cxi = cell - cyi * fsz;
    float fst = (float)stride;
    ax = ((float)cxi + 0.5f) * fst;
    ay = ((float)cyi + 0.5f) * fst;
    float side = (float)(stride * 4);
    float area = side * side;
    int ri = a / 3, si = a - ri * 3;
    float ratio = (ri == 0) ? 0.5f : ((ri == 1) ? 1.0f : 2.0f);
    float scl = (si == 0) ? 1.0f
              : ((si == 1) ? 1.25992104989487316476721f
                           : 1.58740105196819947475170564f);
    float h = sqrtf(area / ratio);
    float w = area / h;
    aw = scl * w;
    ah = scl * h;
}

// counters padded to one 64B line each: gcnt[sub*16]
__device__ __forceinline__ void emit_one(int b, unsigned el, float x, unsigned stripe,
                                         unsigned long long* glist, unsigned* gcnt) {
    unsigned anchor = el / 84u;
    unsigned col = el - anchor * 84u;
    int c = (int)col - 4;
    unsigned key = mono_key(sigmoid_f(x));
    unsigned sub = (unsigned)(b * NCLS + c) * NSTRIPE + stripe;
    unsigned pos = atomicAdd(&gcnt[sub << 4], 1u);
    if (pos < SCAP)
        glist[(size_t)sub * SCAP + pos] =
            ((unsigned long long)key << 32) | (unsigned long long)(0xFFFFFFFFu - anchor);
}

// ---------------- Kernel 1: threshold-collect (pure-ILP stream + dense tail) --
__global__ __launch_bounds__(256) void collect_kernel(const float* __restrict__ pred,
                                                      unsigned long long* __restrict__ glist,
                                                      unsigned* __restrict__ gcnt) {
    __shared__ unsigned pend[512];
    __shared__ unsigned s_p;
    int b = blockIdx.y;
    int tid = threadIdx.x;
    unsigned stripe = (unsigned)blockIdx.x & (NSTRIPE - 1u);
    if (tid == 0) s_p = 0u;
    __syncthreads();
    const float4* p4 = (const float4*)(pred + (size_t)b * EL_PER_IMG);
    unsigned base4 = (unsigned)blockIdx.x * 2560u + (unsigned)tid;

    // phase A: 10 independent loads fully in flight, then test
    float4 v[10];
    unsigned fidx[10];
#pragma unroll
    for (int k = 0; k < 10; k++) {
        unsigned f = base4 + (unsigned)k * 256u;
        fidx[k] = f;
        unsigned fc = (f < (unsigned)F4_PER_IMG) ? f : (unsigned)(F4_PER_IMG - 1);
        v[k] = p4[fc];
    }
#pragma unroll
    for (int k = 0; k < 10; k++) {
        unsigned f = fidx[k];
        bool ok = (f < (unsigned)F4_PER_IMG) && (f % 21u != 0u);  // %21==0 => box cols
        float4 w = v[k];
        if (ok && (w.x >= XCUT || w.y >= XCUT || w.z >= XCUT || w.w >= XCUT)) {
#pragma unroll
            for (int j = 0; j < 4; j++) {
                float x = (j == 0) ? w.x : (j == 1) ? w.y : (j == 2) ? w.z : w.w;
                if (x >= XCUT) {
                    unsigned pos = atomicAdd(&s_p, 1u);
                    unsigned el = f * 4u + (unsigned)j;
                    if (pos < 512u) pend[pos] = el;
                    else emit_one(b, el, x, stripe, glist, gcnt);  // overflow net
                }
            }
        }
    }
    __syncthreads();
    // phase B: dense tail — f64 sigmoid + striped atomic emit (~135/block)
    unsigned np = s_p; if (np > 512u) np = 512u;
    for (unsigned i = (unsigned)tid; i < np; i += 256u) {
        unsigned el = pend[i];
        float x = pred[(size_t)b * EL_PER_IMG + el];
        emit_one(b, el, x, stripe, glist, gcnt);
    }
}

// parallel suffix (inclusive, from high index down) over 2048 u32 in LDS, 512 thr
__device__ __forceinline__ void suffix_scan_2048(unsigned* h, int tid) {
    for (unsigned off = 1; off < 2048; off <<= 1) {
        unsigned v[4];
#pragma unroll
        for (int q = 0; q < 4; q++) {
            unsigned t = (unsigned)tid + q * 512u;
            v[q] = (t + off < 2048u) ? h[t + off] : 0u;
        }
        __syncthreads();
#pragma unroll
        for (int q = 0; q < 4; q++) h[tid + q * 512] += v[q];
        __syncthreads();
    }
}

// ---------------- Kernel 2: gather sub-lists + sort + proof + bitmask NMS -----
__global__ __launch_bounds__(512) void select_nms_kernel(
        const float* __restrict__ pred, const unsigned long long* __restrict__ glist,
        const unsigned* __restrict__ gcnt,
        float* __restrict__ cls_scores, float* __restrict__ cls_boxes) {
    int bc = blockIdx.x;
    int b = bc / NCLS, c = bc - b * NCLS;
    int tid = threadIdx.x;

    __shared__ unsigned long long clist[2048];        // 16 KB
    __shared__ unsigned rowb[512 * 17];               // 34.8 KB NMS rows / fallback hist+eqlist
    __shared__ float4 sbox[PREK];                     // 8 KB
    __shared__ float sarea[PREK];                     // 2 KB
    __shared__ int svalid[PREK];                      // 2 KB
    __shared__ unsigned scnt[NSTRIPE], soff[NSTRIPE];
    __shared__ unsigned keepw[16];
    __shared__ unsigned wsum[8];
    __shared__ int s_ok;
    __shared__ unsigned s_total;
    __shared__ unsigned sh_t, sh_above, s_cnt, s_eq;

    const unsigned KCUT = mono_key(sigmoid_f(XCUT));

    if (tid < NSTRIPE)
        scnt[tid] = gcnt[(((unsigned)bc * NSTRIPE + (unsigned)tid) << 4)];
    for (int i = tid; i < 2048; i += 512) clist[i] = 0ull;
    if (tid == 0) {
        unsigned o = 0; int ok = 1;
        for (int s = 0; s < NSTRIPE; s++) {
            unsigned cs_ = scnt[s];
            if (cs_ > SCAP) ok = 0;
            soff[s] = o;
            o += (cs_ < SCAP ? cs_ : SCAP);
        }
        s_total = o;
        s_ok = ok && (o >= PREK);
    }
    __syncthreads();
    for (int s = 0; s < NSTRIPE; s++) {
        unsigned cs_ = scnt[s]; if (cs_ > SCAP) cs_ = SCAP;
        unsigned o = soff[s];
        const unsigned long long* gp = glist + (size_t)((unsigned)bc * NSTRIPE + s) * SCAP;
        for (unsigned i = (unsigned)tid; i < cs_; i += 512u) clist[o + i] = gp[i];
    }
    __syncthreads();

    bool fast = (s_ok != 0);
    if (fast) {
        // bitonic sort 2048 u64 descending (key desc, index asc via ~idx low32)
        for (unsigned kk = 2; kk <= 2048; kk <<= 1)
            for (unsigned j = kk >> 1; j > 0; j >>= 1) {
#pragma unroll
                for (int q = 0; q < 4; q++) {
                    unsigned i = (unsigned)tid + q * 512u;
                    unsigned ixj = i ^ j;
                    if (ixj > i) {
                        unsigned long long a = clist[i], bb = clist[ixj];
                        bool desc = ((i & kk) == 0u);
                        if (desc ? (a < bb) : (a > bb)) { clist[i] = bb; clist[ixj] = a; }
                    }
                }
                __syncthreads();
            }
        unsigned key511 = (unsigned)(clist[511] >> 32);
        fast = key511 > KCUT;   // every key > KCUT was collected => exact top-512
    }

    if (!fast) {
        // exact 3-level radix-select fallback (never taken on bench input)
        unsigned* hist = (unsigned*)rowb;
        unsigned* eqlist = hist + 2048;
        const float* predc = pred + (size_t)b * NANCH * 84 + 4 + c;
        auto getkey = [&](int i) -> unsigned {
            return mono_key(sigmoid_f(predc[(size_t)i * 84]));
        };
        for (int t = tid; t < 2048; t += 512) hist[t] = 0u;
        __syncthreads();
        for (int i = tid; i < NANCH; i += 512) atomicAdd(&hist[getkey(i) >> 21], 1u);
        __syncthreads();
        suffix_scan_2048(hist, tid);
        unsigned target = PREK;
#pragma unroll
        for (int q = 0; q < 4; q++) {
            int t = tid + q * 512;
            unsigned St = hist[t], St1 = (t < 2047) ? hist[t + 1] : 0u;
            if (St >= target && St1 < target) { sh_t = (unsigned)t; sh_above = St1; }
        }
        __syncthreads();
        unsigned t0 = sh_t, above = sh_above;
        __syncthreads();
        for (int t = tid; t < 2048; t += 512) hist[t] = 0u;
        __syncthreads();
        for (int i = tid; i < NANCH; i += 512) {
            unsigned k = getkey(i);
            if ((k >> 21) == t0) atomicAdd(&hist[(k >> 10) & 0x7FFu], 1u);
        }
        __syncthreads();
        suffix_scan_2048(hist, tid);
        target = PREK - above;
#pragma unroll
        for (int q = 0; q < 4; q++) {
            int t = tid + q * 512;
            unsigned St = hist[t], St1 = (t < 2047) ? hist[t + 1] : 0u;
            if (St >= target && St1 < target) { sh_t = (unsigned)t; sh_above = St1; }
        }
        __syncthreads();
        unsigned t1 = sh_t; above += sh_above;
        __syncthreads();
        for (int t = tid; t < 2048; t += 512) hist[t] = 0u;
        __syncthreads();
        unsigned pfx2 = (t0 << 11) | t1;
        for (int i = tid; i < NANCH; i += 512) {
            unsigned k = getkey(i);
            if ((k >> 10) == pfx2) atomicAdd(&hist[k & 0x3FFu], 1u);
        }
        __syncthreads();
        suffix_scan_2048(hist, tid);
        target = PREK - above;
#pragma unroll
        for (int q = 0; q < 4; q++) {
            int t = tid + q * 512;
            unsigned St = hist[t], St1 = (t < 2047) ? hist[t + 1] : 0u;
            if (St >= target && St1 < target) { sh_t = (unsigned)t; sh_above = St1; }
        }
        __syncthreads();
        unsigned t2 = sh_t; above += sh_above;
        unsigned B = (t0 << 21) | (t1 << 10) | t2;
        unsigned R = PREK - above;
        if (tid == 0) { s_cnt = 0u; s_eq = 0u; }
        __syncthreads();
        for (int i = tid; i < NANCH; i += 512) {
            unsigned k = getkey(i);
            if (k > B) {
                unsigned p = atomicAdd(&s_cnt, 1u);
                clist[p] = ((unsigned long long)k << 32) | (unsigned long long)(0xFFFFFFFFu - (unsigned)i);
            } else if (k == B) {
                unsigned p = atomicAdd(&s_eq, 1u);
                if (p < 1024u) eqlist[p] = (unsigned)i;
            }
        }
        __syncthreads();
        unsigned eqn = s_eq < 1024u ? s_eq : 1024u;
        for (int t = tid; t < 1024; t += 512)
            if ((unsigned)t >= eqn) eqlist[t] = 0xFFFFFFFFu;
        __syncthreads();
        for (unsigned k2 = 2; k2 <= 1024; k2 <<= 1)
            for (unsigned j = k2 >> 1; j > 0; j >>= 1) {
                for (int i = tid; i < 1024; i += 512) {
                    unsigned ixj = (unsigned)i ^ j;
                    if (ixj > (unsigned)i) {
                        unsigned a = eqlist[i], bb = eqlist[ixj];
                        bool asc = (((unsigned)i & k2) == 0u);
                        if (asc ? (a > bb) : (a < bb)) { eqlist[i] = bb; eqlist[ixj] = a; }
                    }
                }
                __syncthreads();
            }
        for (unsigned t = tid; t < R; t += 512) {
            unsigned idxe = eqlist[t];
            clist[above + t] = ((unsigned long long)B << 32) | (unsigned long long)(0xFFFFFFFFu - idxe);
        }
        __syncthreads();
        for (unsigned k2 = 2; k2 <= PREK; k2 <<= 1)
            for (unsigned j = k2 >> 1; j > 0; j >>= 1) {
                unsigned i = (unsigned)tid, ixj = i ^ j;
                if (ixj > i) {
                    unsigned long long a = clist[i], bb = clist[ixj];
                    bool desc = ((i & k2) == 0u);
                    if (desc ? (a < bb) : (a > bb)) { clist[i] = bb; clist[ixj] = a; }
                }
                __syncthreads();
            }
    }
    __syncthreads();

    // ---- decode the 512 sorted candidates ----
    unsigned long long e = clist[tid];
    unsigned key = (unsigned)(e >> 32);
    unsigned aidx = 0xFFFFFFFFu - (unsigned)(e & 0xFFFFFFFFull);
    float score = mono_val(key);
    const float4 pv = *(const float4*)(pred + ((size_t)b * NANCH + aidx) * 84);
    float ax, ay, aw, ah;
    anchor_at((int)aidx, ax, ay, aw, ah);
    float bx = pv.x * 0.1f, by = pv.y * 0.1f, bw2 = pv.z * 0.2f, bh2 = pv.w * 0.2f;
    float cx = bx * aw + ax, cy = by * ah + ay;
    float w = (float)exp((double)bw2) * aw;
    float h = (float)exp((double)bh2) * ah;
    float x1 = cx - w * 0.5f, y1 = cy - h * 0.5f;
    float x2 = cx + w * 0.5f, y2 = cy + h * 0.5f;
    float area = (x2 - x1) * (y2 - y1);
    sbox[tid] = make_float4(x1, y1, x2, y2);
    sarea[tid] = area;
    int validr = (score > CONF_THRF) ? 1 : 0;
    svalid[tid] = validr;
    __syncthreads();

    // ---- build 512x512 suppression bit-matrix (triangular by wave) ----
    int w_ = tid >> 6;
#pragma unroll
    for (int t = 0; t < 8; t++) {
        if (t < w_) {
            rowb[tid * 17 + 2 * t] = 0u;
            rowb[tid * 17 + 2 * t + 1] = 0u;
        } else {
            unsigned m0 = 0u, m1 = 0u;
            for (int jj = 0; jj < 64; jj++) {
                int j = t * 64 + jj;
                float4 bj = sbox[j];
                float aj = sarea[j];
                float xx1 = fmaxf(x1, bj.x);
                float yy1 = fmaxf(y1, bj.y);
                float xx2 = fminf(x2, bj.z);
                float yy2 = fminf(y2, bj.w);
                float ww = fmaxf(xx2 - xx1, 0.0f);
                float hh = fmaxf(yy2 - yy1, 0.0f);
                float inter = ww * hh;
                float uni = area + aj - inter;
                float iou = inter / fmaxf(uni, 1e-8f);   // exact reference arithmetic
                bool sup = (iou > IOU_THRF) && (j > tid) && validr;
                if (jj < 32) m0 |= sup ? (1u << jj) : 0u;
                else         m1 |= sup ? (1u << (jj - 32)) : 0u;
            }
            rowb[tid * 17 + 2 * t] = m0;
            rowb[tid * 17 + 2 * t + 1] = m1;
        }
    }
    __syncthreads();

    // ---- resolve: chunked broadcast, dependent chain is 2 VALU ops/step ----
    if (tid < 64) {
        int w16 = tid & 15;
        unsigned kw = 0xFFFFFFFFu;   // word w16 of keep mask (replicated across lane groups)
        for (int cch = 0; cch < 16; cch++) {
            unsigned local = (unsigned)__shfl((int)kw, cch);  // keep-word of this chunk
            for (int ii = 0; ii < 32; ii++) {
                int i = cch * 32 + ii;
                unsigned rb = rowb[i * 17 + w16];   // per-lane word of row i (off-chain)
                unsigned rw = rowb[i * 17 + cch];   // broadcast word (off-chain)
                if ((local >> ii) & 1u) {           // uniform branch (local uniform)
                    local &= ~rw;
                    kw &= ~rb;
                }
            }
        }
        if (tid < 16) keepw[tid] = kw;
    }
    __syncthreads();

    // ---- ballot compaction -> per-class top-100 ----
    unsigned kbit = (keepw[tid >> 5] >> (tid & 31)) & 1u;
    int kept = (int)kbit & svalid[tid];
    unsigned long long bal = __ballot(kept != 0);
    int lane6 = tid & 63;
    if (lane6 == 0) wsum[w_] = (unsigned)__popcll(bal);
    __syncthreads();
    int rank = 0;
    for (int u = 0; u < w_; u++) rank += (int)wsum[u];
    rank += (int)__popcll(bal & ((1ull << lane6) - 1ull));

    float* cs = cls_scores + (size_t)bc * MAXDET;
    float* cb = cls_boxes + (size_t)bc * MAXDET * 4;
    for (int r = tid; r < MAXDET; r += 512) {
        cs[r] = -1.0f;
        cb[r * 4 + 0] = -1.0f; cb[r * 4 + 1] = -1.0f;
        cb[r * 4 + 2] = -1.0f; cb[r * 4 + 3] = -1.0f;
    }
    __syncthreads();
    if (kept && rank < MAXDET) {
        cs[rank] = score;
        cb[rank * 4 + 0] = cx; cb[rank * 4 + 1] = cy;
        cb[rank * 4 + 2] = w;  cb[rank * 4 + 3] = h;
    }
}

// ---------------- Kernel 3: per-image top-100 of 8000 + masking + count -------
__global__ __launch_bounds__(1024) void final_topk(const float* __restrict__ cls_scores,
                                                   const float* __restrict__ cls_boxes,
                                                   float* __restrict__ out) {
    int b = blockIdx.x;
    int tid = threadIdx.x;
    __shared__ unsigned long long arr[8192];          // 64 KB exactly
    for (int i = tid; i < 8192; i += 1024) {
        if (i < NCLS * MAXDET) {
            float s = cls_scores[(size_t)b * NCLS * MAXDET + i];
            arr[i] = ((unsigned long long)mono_key(s) << 32)
                   | (unsigned long long)(0xFFFFFFFFu - (unsigned)i);
        } else arr[i] = 0ull;
    }
    __syncthreads();
    for (unsigned k = 2; k <= 8192; k <<= 1)
        for (unsigned j = k >> 1; j > 0; j >>= 1) {
#pragma unroll
            for (int q = 0; q < 8; q++) {
                unsigned i = (unsigned)tid + (unsigned)q * 1024u;
                unsigned ixj = i ^ j;
                if (ixj > i) {
                    unsigned long long a = arr[i], bb = arr[ixj];
                    bool desc = ((i & k) == 0u);
                    if (desc ? (a < bb) : (a > bb)) { arr[i] = bb; arr[ixj] = a; }
                }
            }
            __syncthreads();
        }

    bool v = false;
    if (tid < MAXDET) {
        unsigned long long e = arr[tid];
        unsigned mk = (unsigned)(e >> 32);
        float s = mono_val(mk);
        unsigned fi = 0xFFFFFFFFu - (unsigned)(e & 0xFFFFFFFFull);
        v = (s >= CONF_THRF);
        float obx = -1.0f, oby = -1.0f, obw = -1.0f, obh = -1.0f;
        float ofs = -1.0f, ofc = -1.0f;
        if (v) {
            const float* bp = cls_boxes + ((size_t)b * NCLS * MAXDET + fi) * 4;
            obx = bp[0]; oby = bp[1]; obw = bp[2]; obh = bp[3];
            ofs = s;
            ofc = (float)(fi / MAXDET);
        }
        int o = b * MAXDET + tid;
        out[o * 4 + 0] = obx; out[o * 4 + 1] = oby;
        out[o * 4 + 2] = obw; out[o * 4 + 3] = obh;
        out[NIMG * MAXDET * 4 + o] = ofs;
        out[NIMG * MAXDET * 5 + o] = ofc;
    }
    __syncthreads();
    unsigned long long bal = __ballot(v);
    if ((tid & 63) == 0) arr[tid >> 6] = bal;
    __syncthreads();
    if (tid == 0) {
        int cnt2 = 0;
        for (int u = 0; u < 16; u++) cnt2 += (int)__popcll(arr[u]);
        out[NIMG * MAXDET * 6 + b] = (float)cnt2;
    }
}

extern "C" void kernel_launch(void* const* d_in, const int* in_sizes, int n_in,
                              void* d_out, int out_size, void* d_ws, size_t ws_size,
                              hipStream_t stream) {
    (void)in_sizes; (void)n_in; (void)out_size; (void)ws_size;
    const float* pred = (const float*)d_in[1];  // d_in[0] = images (only H=W=640 used)
    float* out = (float*)d_out;

    char* base = (char*)d_ws;
    unsigned* gcnt = (unsigned*)base;                          // 5120 counters x 64B = 327,680 B
    size_t gcnt_bytes = (size_t)NSUB * 16 * sizeof(unsigned);
    unsigned long long* glist = (unsigned long long*)(base + gcnt_bytes);  // 5120*128*8 = 5.24 MB
    size_t glist_bytes = (size_t)NSUB * SCAP * 8u;
    float* cls_scores = (float*)(base + gcnt_bytes + glist_bytes);         // 128 KB
    float* cls_boxes  = cls_scores + (size_t)NIMG * NCLS * MAXDET;         // 512 KB

    hipMemsetAsync(gcnt, 0, gcnt_bytes, stream);
    collect_kernel<<<dim3(630, NIMG), 256, 0, stream>>>(pred, glist, gcnt);
    select_nms_kernel<<<NIMG * NCLS, 512, 0, stream>>>(pred, glist, gcnt, cls_scores, cls_boxes);
    final_topk<<<NIMG, 1024, 0, stream>>>(cls_scores, cls_boxes, out);
}

// Round 4
// 364.013 us; speedup vs baseline: 2.0129x; 1.1869x over previous
//
#include <hip/hip_runtime.h>
#include <math.h>

#define NANCH 76725
#define NCLS 80
#define NIMG 4
#define PREK 512
#define MAXDET 100
#define CONF_THRF 0.05f
#define IOU_THRF 0.5f
#define XCUT 2.2f            // logit cut: sigmoid(2.2)=0.90025; 512th-best per class ~0.92
#define NSTRIPE 16           // per-class atomic striping (by blockIdx.x & 15)
#define SCAP 128             // capacity per (class,stripe) sub-list; expected ~67 +/- 8
#define F4_PER_IMG 1611225   // 76725*84/4
#define EL_PER_IMG 6444900   // 76725*84
#define NSUB (NIMG * NCLS * NSTRIPE)   // 5120 sub-lists

__device__ __forceinline__ unsigned mono_key(float s) {
    unsigned b = __float_as_uint(s);
    return (b & 0x80000000u) ? ~b : (b | 0x80000000u);
}
__device__ __forceinline__ float mono_val(unsigned k) {
    return (k & 0x80000000u) ? __uint_as_float(k ^ 0x80000000u) : __uint_as_float(~k);
}
// Correctly-rounded-to-f32 sigmoid via double; matched XLA exactly (absmax 0.0 r1-r3).
__device__ __forceinline__ float sigmoid_f(float x) {
    return (float)(1.0 / (1.0 + exp(-(double)x)));
}

__device__ __forceinline__ unsigned long long shflx64(unsigned long long v, int d) {
    unsigned lo = (unsigned)v, hi = (unsigned)(v >> 32);
    lo = (unsigned)__shfl_xor((int)lo, d, 64);
    hi = (unsigned)__shfl_xor((int)hi, d, 64);
    return ((unsigned long long)hi << 32) | (unsigned long long)lo;
}
// bitonic compare-exchange result for element idx against partner value u (dir from k,j)
__device__ __forceinline__ unsigned long long ce_dir(unsigned long long v, unsigned long long u,
                                                     unsigned idx, unsigned j, unsigned k) {
    bool take_max = (((idx & k) == 0u) == ((idx & j) == 0u));
    bool u_gt = (u > v);
    return (take_max == u_gt) ? u : v;
}

// RetinaNet anchors, levels 3..7, 640x640, xywh. Replicates reference float32 math.
__device__ void anchor_at(int idx, float& ax, float& ay, float& aw, float& ah) {
    int l, li = idx;
    if (idx < 57600)      { l = 0; }
    else if (idx < 72000) { l = 1; li = idx - 57600; }
    else if (idx < 75600) { l = 2; li = idx - 72000; }
    else if (idx < 76500) { l = 3; li = idx - 75600; }
    else                  { l = 4; li = idx - 76500; }
    int stride = 8 << l;
    int fsz = 640 >> (3 + l);
    int cell = li / 9, a = li - cell * 9;
    int cyi = cell / fsz, cxi = cell - cyi * fsz;
    float fst = (float)stride;
    ax = ((float)cxi + 0.5f) * fst;
    ay = ((float)cyi + 0.5f) * fst;
    float side = (float)(stride * 4);
    float area = side * side;
    int ri = a / 3, si = a - ri * 3;
    float ratio = (ri == 0) ? 0.5f : ((ri == 1) ? 1.0f : 2.0f);
    float scl = (si == 0) ? 1.0f
              : ((si == 1) ? 1.25992104989487316476721f
                           : 1.58740105196819947475170564f);
    float h = sqrtf(area / ratio);
    float w = area / h;
    aw = scl * w;
    ah = scl * h;
}

// counters padded to one 64B line each: gcnt[sub*16]
__device__ __forceinline__ void emit_one(int b, unsigned el, float x, unsigned stripe,
                                         unsigned long long* glist, unsigned* gcnt) {
    unsigned anchor = el / 84u;
    unsigned col = el - anchor * 84u;
    int c = (int)col - 4;
    unsigned key = mono_key(sigmoid_f(x));
    unsigned sub = (unsigned)(b * NCLS + c) * NSTRIPE + stripe;
    unsigned pos = atomicAdd(&gcnt[sub << 4], 1u);
    if (pos < SCAP)
        glist[(size_t)sub * SCAP + pos] =
            ((unsigned long long)key << 32) | (unsigned long long)(0xFFFFFFFFu - anchor);
}

// ---------------- Kernel 1: threshold-collect (pure-ILP stream + dense tail) --
__global__ __launch_bounds__(256) void collect_kernel(const float* __restrict__ pred,
                                                      unsigned long long* __restrict__ glist,
                                                      unsigned* __restrict__ gcnt) {
    __shared__ unsigned pend[512];
    __shared__ unsigned s_p;
    int b = blockIdx.y;
    int tid = threadIdx.x;
    unsigned stripe = (unsigned)blockIdx.x & (NSTRIPE - 1u);
    if (tid == 0) s_p = 0u;
    __syncthreads();
    const float4* p4 = (const float4*)(pred + (size_t)b * EL_PER_IMG);
    unsigned base4 = (unsigned)blockIdx.x * 2560u + (unsigned)tid;

    float4 v[10];
    unsigned fidx[10];
#pragma unroll
    for (int k = 0; k < 10; k++) {
        unsigned f = base4 + (unsigned)k * 256u;
        fidx[k] = f;
        unsigned fc = (f < (unsigned)F4_PER_IMG) ? f : (unsigned)(F4_PER_IMG - 1);
        v[k] = p4[fc];
    }
#pragma unroll
    for (int k = 0; k < 10; k++) {
        unsigned f = fidx[k];
        bool ok = (f < (unsigned)F4_PER_IMG) && (f % 21u != 0u);  // %21==0 => box cols
        float4 w = v[k];
        if (ok && (w.x >= XCUT || w.y >= XCUT || w.z >= XCUT || w.w >= XCUT)) {
#pragma unroll
            for (int j = 0; j < 4; j++) {
                float x = (j == 0) ? w.x : (j == 1) ? w.y : (j == 2) ? w.z : w.w;
                if (x >= XCUT) {
                    unsigned pos = atomicAdd(&s_p, 1u);
                    unsigned el = f * 4u + (unsigned)j;
                    if (pos < 512u) pend[pos] = el;
                    else emit_one(b, el, x, stripe, glist, gcnt);
                }
            }
        }
    }
    __syncthreads();
    unsigned np = s_p; if (np > 512u) np = 512u;
    for (unsigned i = (unsigned)tid; i < np; i += 256u) {
        unsigned el = pend[i];
        float x = pred[(size_t)b * EL_PER_IMG + el];
        emit_one(b, el, x, stripe, glist, gcnt);
    }
}

// parallel suffix (inclusive, from high index down) over 2048 u32 in LDS, 512 thr
__device__ __forceinline__ void suffix_scan_2048(unsigned* h, int tid) {
    for (unsigned off = 1; off < 2048; off <<= 1) {
        unsigned v[4];
#pragma unroll
        for (int q = 0; q < 4; q++) {
            unsigned t = (unsigned)tid + q * 512u;
            v[q] = (t + off < 2048u) ? h[t + off] : 0u;
        }
        __syncthreads();
#pragma unroll
        for (int q = 0; q < 4; q++) h[tid + q * 512] += v[q];
        __syncthreads();
    }
}

// ---------------- Kernel 2: gather + partition + reg-bitonic sort + NMS -------
__global__ __launch_bounds__(512) void select_nms_kernel(
        const float* __restrict__ pred, const unsigned long long* __restrict__ glist,
        const unsigned* __restrict__ gcnt,
        float* __restrict__ cls_scores, float* __restrict__ cls_boxes) {
    int bc = blockIdx.x;
    int b = bc / NCLS, c = bc - b * NCLS;
    int tid = threadIdx.x;

    __shared__ unsigned long long clist[2048];             // 16 KB raw gather
    __shared__ __align__(16) unsigned rowb[512 * 17];      // 34.8 KB multi-use:
                                                           //  fast: sout[1024] u64 (words 0..2047) + hist[512] (2048..2559)
                                                           //  NMS:  512 bit-rows stride 17
                                                           //  fallback: hist[2048] + eqlist[1024]
    __shared__ float4 sbox[PREK];
    __shared__ float sarea[PREK];
    __shared__ int svalid[PREK];
    __shared__ unsigned scnt[NSTRIPE], soff[NSTRIPE];
    __shared__ unsigned keepw[16];
    __shared__ unsigned wsum[8];
    __shared__ int s_ok;
    __shared__ unsigned s_total, s_tb, s_A, a_ctr, e_ctr, s_fail;
    __shared__ unsigned sh_t, sh_above, s_cnt, s_eq;

    unsigned long long* sout = (unsigned long long*)rowb;  // 1024 u64
    unsigned* hist = rowb + 2048;                          // 512 bins

    const unsigned KCUT = mono_key(sigmoid_f(XCUT));
    const unsigned BASE = KCUT >> 12;                      // fast keys in (KCUT, mono(1.0f)] -> bins [0,410]

    if (tid < NSTRIPE)
        scnt[tid] = gcnt[(((unsigned)bc * NSTRIPE + (unsigned)tid) << 4)];
    for (int i = tid; i < 2048; i += 512) clist[i] = 0ull;
    for (int i = tid; i < 1024; i += 512) sout[i] = 0ull;
    hist[tid] = 0u;
    if (tid == 0) { a_ctr = 0u; e_ctr = 0u; s_fail = 0u; }
    __syncthreads();
    if (tid == 0) {
        unsigned o = 0; int ok = 1;
        for (int s = 0; s < NSTRIPE; s++) {
            unsigned cs_ = scnt[s];
            if (cs_ > SCAP) ok = 0;
            soff[s] = o;
            o += (cs_ < SCAP ? cs_ : SCAP);
        }
        s_total = o;
        s_ok = ok && (o >= PREK);
    }
    __syncthreads();
    // gather sub-lists + histogram key>>12 bins
    for (int s = 0; s < NSTRIPE; s++) {
        unsigned cs_ = scnt[s]; if (cs_ > SCAP) cs_ = SCAP;
        unsigned o = soff[s];
        const unsigned long long* gp = glist + (size_t)((unsigned)bc * NSTRIPE + s) * SCAP;
        for (unsigned i = (unsigned)tid; i < cs_; i += 512u) {
            unsigned long long e2 = gp[i];
            clist[o + i] = e2;
            int bin = (int)((unsigned)(e2 >> 32) >> 12) - (int)BASE;
            bin = bin < 0 ? 0 : (bin > 511 ? 511 : bin);
            atomicAdd(&hist[bin], 1u);
        }
    }
    __syncthreads();

    bool fastb = (s_ok != 0);
    if (fastb) {
        // suffix scan over 512 bins: wave shfl + cross-wave combine
        unsigned vbin = hist[tid];
        int lane = tid & 63, w8 = tid >> 6;
#pragma unroll
        for (int off = 1; off < 64; off <<= 1) {
            unsigned u = (unsigned)__shfl_down((int)vbin, off, 64);
            if (lane + off < 64) vbin += u;
        }
        if (lane == 0) wsum[w8] = vbin;
        __syncthreads();
        if (tid == 0) {
            unsigned acc = 0;
            for (int w = 7; w >= 0; w--) { unsigned t = wsum[w]; wsum[w] = acc; acc += t; }
        }
        __syncthreads();
        vbin += wsum[w8];
        hist[tid] = vbin;          // suffix counts
        __syncthreads();
        unsigned S = vbin, S1 = (tid < 511) ? hist[tid + 1] : 0u;
        if (S >= PREK && S1 < PREK) { s_tb = (unsigned)tid; s_A = S1; }
        __syncthreads();
        unsigned tb = s_tb;
        unsigned total = s_total;
        // recollect: above-set -> sout[0..A), boundary bin -> sout[512..512+eq)
        for (unsigned i = (unsigned)tid; i < total; i += 512u) {
            unsigned long long e2 = clist[i];
            int bin = (int)((unsigned)(e2 >> 32) >> 12) - (int)BASE;
            bin = bin < 0 ? 0 : (bin > 511 ? 511 : bin);
            if ((unsigned)bin > tb) {
                unsigned p = atomicAdd(&a_ctr, 1u);
                sout[p] = e2;                          // p < 512 guaranteed (= suffix(tb+1))
            } else if ((unsigned)bin == tb) {
                unsigned p = atomicAdd(&e_ctr, 1u);
                if (p < 512u) sout[512u + p] = e2;
                else s_fail = 1u;
            }
        }
        __syncthreads();
        if (s_fail) fastb = false;
    }
    if (fastb) {
        // register bitonic sort of sout[0..1024) descending; idx = 2*tid + e
        unsigned i0 = (unsigned)tid * 2u, i1 = i0 + 1u;
        unsigned long long v0 = sout[i0], v1 = sout[i1];
        for (unsigned k = 2; k <= 1024; k <<= 1) {
            for (unsigned j = k >> 1; j >= 1; j >>= 1) {
                if (j >= 128) {
                    sout[i0] = v0; sout[i1] = v1;
                    __syncthreads();
                    unsigned long long u0 = sout[i0 ^ j], u1 = sout[i1 ^ j];
                    v0 = ce_dir(v0, u0, i0, j, k);
                    v1 = ce_dir(v1, u1, i1, j, k);
                    __syncthreads();
                } else if (j >= 2) {
                    int d = (int)(j >> 1);
                    unsigned long long u0 = shflx64(v0, d), u1 = shflx64(v1, d);
                    v0 = ce_dir(v0, u0, i0, j, k);
                    v1 = ce_dir(v1, u1, i1, j, k);
                } else {
                    bool tm = ((i0 & k) == 0u);
                    unsigned long long mx = v0 > v1 ? v0 : v1;
                    unsigned long long mn = v0 > v1 ? v1 : v0;
                    v0 = tm ? mx : mn; v1 = tm ? mn : mx;
                }
            }
        }
        sout[i0] = v0; sout[i1] = v1;
        __syncthreads();
        unsigned key511 = (unsigned)(sout[511] >> 32);
        fastb = key511 > KCUT;     // proof: every uncollected key <= KCUT
    }

    if (!fastb) {
        // exact 3-level radix-select fallback (never taken on bench input)
        unsigned* fhist = rowb;
        unsigned* eqlist = rowb + 2048;
        const float* predc = pred + (size_t)b * NANCH * 84 + 4 + c;
        auto getkey = [&](int i) -> unsigned {
            return mono_key(sigmoid_f(predc[(size_t)i * 84]));
        };
        __syncthreads();
        for (int t = tid; t < 2048; t += 512) fhist[t] = 0u;
        __syncthreads();
        for (int i = tid; i < NANCH; i += 512) atomicAdd(&fhist[getkey(i) >> 21], 1u);
        __syncthreads();
        suffix_scan_2048(fhist, tid);
        unsigned target = PREK;
#pragma unroll
        for (int q = 0; q < 4; q++) {
            int t = tid + q * 512;
            unsigned St = fhist[t], St1 = (t < 2047) ? fhist[t + 1] : 0u;
            if (St >= target && St1 < target) { sh_t = (unsigned)t; sh_above = St1; }
        }
        __syncthreads();
        unsigned t0 = sh_t, above = sh_above;
        __syncthreads();
        for (int t = tid; t < 2048; t += 512) fhist[t] = 0u;
        __syncthreads();
        for (int i = tid; i < NANCH; i += 512) {
            unsigned k = getkey(i);
            if ((k >> 21) == t0) atomicAdd(&fhist[(k >> 10) & 0x7FFu], 1u);
        }
        __syncthreads();
        suffix_scan_2048(fhist, tid);
        target = PREK - above;
#pragma unroll
        for (int q = 0; q < 4; q++) {
            int t = tid + q * 512;
            unsigned St = fhist[t], St1 = (t < 2047) ? fhist[t + 1] : 0u;
            if (St >= target && St1 < target) { sh_t = (unsigned)t; sh_above = St1; }
        }
        __syncthreads();
        unsigned t1 = sh_t; above += sh_above;
        __syncthreads();
        for (int t = tid; t < 2048; t += 512) fhist[t] = 0u;
        __syncthreads();
        unsigned pfx2 = (t0 << 11) | t1;
        for (int i = tid; i < NANCH; i += 512) {
            unsigned k = getkey(i);
            if ((k >> 10) == pfx2) atomicAdd(&fhist[k & 0x3FFu], 1u);
        }
        __syncthreads();
        suffix_scan_2048(fhist, tid);
        target = PREK - above;
#pragma unroll
        for (int q = 0; q < 4; q++) {
            int t = tid + q * 512;
            unsigned St = fhist[t], St1 = (t < 2047) ? fhist[t + 1] : 0u;
            if (St >= target && St1 < target) { sh_t = (unsigned)t; sh_above = St1; }
        }
        __syncthreads();
        unsigned t2 = sh_t; above += sh_above;
        unsigned B = (t0 << 21) | (t1 << 10) | t2;
        unsigned R = PREK - above;
        if (tid == 0) { s_cnt = 0u; s_eq = 0u; }
        __syncthreads();
        for (int i = tid; i < NANCH; i += 512) {
            unsigned k = getkey(i);
            if (k > B) {
                unsigned p = atomicAdd(&s_cnt, 1u);
                clist[p] = ((unsigned long long)k << 32) | (unsigned long long)(0xFFFFFFFFu - (unsigned)i);
            } else if (k == B) {
                unsigned p = atomicAdd(&s_eq, 1u);
                if (p < 1024u) eqlist[p] = (unsigned)i;
            }
        }
        __syncthreads();
        unsigned eqn = s_eq < 1024u ? s_eq : 1024u;
        for (int t = tid; t < 1024; t += 512)
            if ((unsigned)t >= eqn) eqlist[t] = 0xFFFFFFFFu;
        __syncthreads();
        for (unsigned k2 = 2; k2 <= 1024; k2 <<= 1)
            for (unsigned j = k2 >> 1; j > 0; j >>= 1) {
                for (int i = tid; i < 1024; i += 512) {
                    unsigned ixj = (unsigned)i ^ j;
                    if (ixj > (unsigned)i) {
                        unsigned a = eqlist[i], bb = eqlist[ixj];
                        bool asc = (((unsigned)i & k2) == 0u);
                        if (asc ? (a > bb) : (a < bb)) { eqlist[i] = bb; eqlist[ixj] = a; }
                    }
                }
                __syncthreads();
            }
        for (unsigned t = tid; t < R; t += 512) {
            unsigned idxe = eqlist[t];
            clist[above + t] = ((unsigned long long)B << 32) | (unsigned long long)(0xFFFFFFFFu - idxe);
        }
        __syncthreads();
        for (unsigned k2 = 2; k2 <= PREK; k2 <<= 1)
            for (unsigned j = k2 >> 1; j > 0; j >>= 1) {
                unsigned i = (unsigned)tid, ixj = i ^ j;
                if (ixj > i) {
                    unsigned long long a = clist[i], bb = clist[ixj];
                    bool desc = ((i & k2) == 0u);
                    if (desc ? (a < bb) : (a > bb)) { clist[i] = bb; clist[ixj] = a; }
                }
                __syncthreads();
            }
        __syncthreads();
    }

    // ---- decode the 512 sorted candidates ----
    unsigned long long e = fastb ? sout[tid] : clist[tid];
    unsigned key = (unsigned)(e >> 32);
    unsigned aidx = 0xFFFFFFFFu - (unsigned)(e & 0xFFFFFFFFull);
    float score = mono_val(key);
    const float4 pv = *(const float4*)(pred + ((size_t)b * NANCH + aidx) * 84);
    float ax, ay, aw, ah;
    anchor_at((int)aidx, ax, ay, aw, ah);
    float bx = pv.x * 0.1f, by = pv.y * 0.1f, bw2 = pv.z * 0.2f, bh2 = pv.w * 0.2f;
    float cx = bx * aw + ax, cy = by * ah + ay;
    float w = (float)exp((double)bw2) * aw;
    float h = (float)exp((double)bh2) * ah;
    float x1 = cx - w * 0.5f, y1 = cy - h * 0.5f;
    float x2 = cx + w * 0.5f, y2 = cy + h * 0.5f;
    float area = (x2 - x1) * (y2 - y1);
    sbox[tid] = make_float4(x1, y1, x2, y2);
    sarea[tid] = area;
    int validr = (score > CONF_THRF) ? 1 : 0;
    svalid[tid] = validr;
    __syncthreads();               // everyone has read sout/clist; rowb reusable now

    // ---- prezero bit-rows, then balanced triangular build ----
    for (int i = tid; i < 512 * 17; i += 512) rowb[i] = 0u;
    __syncthreads();
    int w_ = tid >> 6, lane6 = tid & 63;
    for (int p = w_; p < 36; p += 8) {
        int rw = 0, basep = 0;
        while (basep + (8 - rw) <= p) { basep += 8 - rw; rw++; }
        int ct = rw + (p - basep);
        int r = rw * 64 + lane6;
        float4 br = sbox[r];
        float ar = sarea[r];
        int vr = svalid[r];
        unsigned m0 = 0u, m1 = 0u;
        for (int jj = 0; jj < 64; jj++) {
            int j = ct * 64 + jj;
            float4 bj = sbox[j];               // uniform j -> LDS broadcast
            float aj = sarea[j];
            float xx1 = fmaxf(br.x, bj.x);
            float yy1 = fmaxf(br.y, bj.y);
            float xx2 = fminf(br.z, bj.z);
            float yy2 = fminf(br.w, bj.w);
            float ww = fmaxf(xx2 - xx1, 0.0f);
            float hh = fmaxf(yy2 - yy1, 0.0f);
            float inter = ww * hh;
            float uni = ar + aj - inter;
            float iou = inter / fmaxf(uni, 1e-8f);   // exact reference arithmetic
            bool sup = (iou > IOU_THRF) && (j > r) && vr;
            if (jj < 32) m0 |= sup ? (1u << jj) : 0u;
            else         m1 |= sup ? (1u << (jj - 32)) : 0u;
        }
        rowb[r * 17 + 2 * ct] = m0;
        rowb[r * 17 + 2 * ct + 1] = m1;
    }
    __syncthreads();

    // ---- resolve: chunked broadcast, 2-VALU dependent chain per step ----
    if (tid < 64) {
        int w16 = tid & 15;
        unsigned kw = 0xFFFFFFFFu;
        for (int cch = 0; cch < 16; cch++) {
            unsigned local = (unsigned)__shfl((int)kw, cch);
            for (int ii = 0; ii < 32; ii++) {
                int i = cch * 32 + ii;
                unsigned rb = rowb[i * 17 + w16];
                unsigned rw2 = rowb[i * 17 + cch];
                if ((local >> ii) & 1u) {
                    local &= ~rw2;
                    kw &= ~rb;
                }
            }
        }
        if (tid < 16) keepw[tid] = kw;
    }
    __syncthreads();

    // ---- ballot compaction -> per-class top-100 ----
    unsigned kbit = (keepw[tid >> 5] >> (tid & 31)) & 1u;
    int kept = (int)kbit & svalid[tid];
    unsigned long long bal = __ballot(kept != 0);
    if (lane6 == 0) wsum[w_] = (unsigned)__popcll(bal);
    __syncthreads();
    int rank = 0;
    for (int u = 0; u < w_; u++) rank += (int)wsum[u];
    rank += (int)__popcll(bal & ((1ull << lane6) - 1ull));

    float* cs = cls_scores + (size_t)bc * MAXDET;
    float* cb = cls_boxes + (size_t)bc * MAXDET * 4;
    for (int r = tid; r < MAXDET; r += 512) {
        cs[r] = -1.0f;
        cb[r * 4 + 0] = -1.0f; cb[r * 4 + 1] = -1.0f;
        cb[r * 4 + 2] = -1.0f; cb[r * 4 + 3] = -1.0f;
    }
    __syncthreads();
    if (kept && rank < MAXDET) {
        cs[rank] = score;
        cb[rank * 4 + 0] = cx; cb[rank * 4 + 1] = cy;
        cb[rank * 4 + 2] = w;  cb[rank * 4 + 3] = h;
    }
}

// ---------------- Kernel 3: per-image top-100 via register bitonic ------------
__global__ __launch_bounds__(1024) void final_topk(const float* __restrict__ cls_scores,
                                                   const float* __restrict__ cls_boxes,
                                                   float* __restrict__ out) {
    int b = blockIdx.x;
    int tid = threadIdx.x;
    __shared__ unsigned long long arr[8192];          // 64 KB staging
    unsigned long long v[8];
    unsigned idx0 = (unsigned)tid * 8u;
#pragma unroll
    for (int e = 0; e < 8; e++) {
        unsigned i = idx0 + (unsigned)e;
        unsigned long long val = 0ull;
        if (i < (unsigned)(NCLS * MAXDET)) {
            float s = cls_scores[(size_t)b * NCLS * MAXDET + i];
            val = ((unsigned long long)mono_key(s) << 32)
                | (unsigned long long)(0xFFFFFFFFu - i);
        }
        v[e] = val;
    }
#pragma unroll 1
    for (unsigned k = 2; k <= 8192; k <<= 1) {
#pragma unroll 1
        for (unsigned j = k >> 1; j >= 1; j >>= 1) {
            if (j >= 512) {
#pragma unroll
                for (int e = 0; e < 8; e++) arr[idx0 + e] = v[e];
                __syncthreads();
#pragma unroll
                for (int e = 0; e < 8; e++) {
                    unsigned idx = idx0 + (unsigned)e;
                    unsigned long long u = arr[idx ^ j];
                    v[e] = ce_dir(v[e], u, idx, j, k);
                }
                __syncthreads();
            } else if (j >= 8) {
                int d = (int)(j >> 3);
#pragma unroll
                for (int e = 0; e < 8; e++) {
                    unsigned idx = idx0 + (unsigned)e;
                    unsigned long long u = shflx64(v[e], d);
                    v[e] = ce_dir(v[e], u, idx, j, k);
                }
            } else {
#pragma unroll
                for (int e = 0; e < 8; e++) {
                    if ((e & (int)j) == 0) {
                        int e2 = e | (int)j;
                        unsigned idx = idx0 + (unsigned)e;
                        bool tm = ((idx & k) == 0u);
                        unsigned long long mx = v[e] > v[e2] ? v[e] : v[e2];
                        unsigned long long mn = v[e] > v[e2] ? v[e2] : v[e];
                        v[e] = tm ? mx : mn;
                        v[e2] = tm ? mn : mx;
                    }
                }
            }
        }
    }
#pragma unroll
    for (int e = 0; e < 8; e++) arr[idx0 + e] = v[e];
    __syncthreads();

    bool vd = false;
    if (tid < MAXDET) {
        unsigned long long e = arr[tid];
        unsigned mk = (unsigned)(e >> 32);
        float s = mono_val(mk);
        unsigned fi = 0xFFFFFFFFu - (unsigned)(e & 0xFFFFFFFFull);
        vd = (s >= CONF_THRF);
        float obx = -1.0f, oby = -1.0f, obw = -1.0f, obh = -1.0f;
        float ofs = -1.0f, ofc = -1.0f;
        if (vd) {
            const float* bp = cls_boxes + ((size_t)b * NCLS * MAXDET + fi) * 4;
            obx = bp[0]; oby = bp[1]; obw = bp[2]; obh = bp[3];
            ofs = s;
            ofc = (float)(fi / MAXDET);
        }
        int o = b * MAXDET + tid;
        out[o * 4 + 0] = obx; out[o * 4 + 1] = oby;
        out[o * 4 + 2] = obw; out[o * 4 + 3] = obh;
        out[NIMG * MAXDET * 4 + o] = ofs;
        out[NIMG * MAXDET * 5 + o] = ofc;
    }
    __syncthreads();
    unsigned long long bal = __ballot(vd);
    if ((tid & 63) == 0) arr[tid >> 6] = bal;
    __syncthreads();
    if (tid == 0) {
        int cnt2 = 0;
        for (int u = 0; u < 16; u++) cnt2 += (int)__popcll(arr[u]);
        out[NIMG * MAXDET * 6 + b] = (float)cnt2;
    }
}

extern "C" void kernel_launch(void* const* d_in, const int* in_sizes, int n_in,
                              void* d_out, int out_size, void* d_ws, size_t ws_size,
                              hipStream_t stream) {
    (void)in_sizes; (void)n_in; (void)out_size; (void)ws_size;
    const float* pred = (const float*)d_in[1];  // d_in[0] = images (only H=W=640 used)
    float* out = (float*)d_out;

    char* base = (char*)d_ws;
    unsigned* gcnt = (unsigned*)base;                          // 5120 counters x 64B
    size_t gcnt_bytes = (size_t)NSUB * 16 * sizeof(unsigned);
    unsigned long long* glist = (unsigned long long*)(base + gcnt_bytes);  // 5.24 MB
    size_t glist_bytes = (size_t)NSUB * SCAP * 8u;
    float* cls_scores = (float*)(base + gcnt_bytes + glist_bytes);
    float* cls_boxes  = cls_scores + (size_t)NIMG * NCLS * MAXDET;

    hipMemsetAsync(gcnt, 0, gcnt_bytes, stream);
    collect_kernel<<<dim3(630, NIMG), 256, 0, stream>>>(pred, glist, gcnt);
    select_nms_kernel<<<NIMG * NCLS, 512, 0, stream>>>(pred, glist, gcnt, cls_scores, cls_boxes);
    final_topk<<<NIMG, 1024, 0, stream>>>(cls_scores, cls_boxes, out);
}

// Round 5
// 363.389 us; speedup vs baseline: 2.0164x; 1.0017x over previous
//
#include <hip/hip_runtime.h>
#include <math.h>

#define NANCH 76725
#define NCLS 80
#define NIMG 4
#define PREK 512
#define MAXDET 100
#define CONF_THRF 0.05f
#define IOU_THRF 0.5f
#define XCUT 2.2f            // logit cut: sigmoid(2.2)=0.90025; 512th-best per class ~0.92
#define NSTRIPE 16           // per-class atomic striping (by blockIdx.x & 15)
#define SCAP 128             // capacity per (class,stripe) sub-list; expected ~67 +/- 8
#define F4_PER_IMG 1611225   // 76725*84/4
#define EL_PER_IMG 6444900   // 76725*84
#define NSUB (NIMG * NCLS * NSTRIPE)   // 5120 sub-lists
#define NBC (NIMG * NCLS)              // 320 (image,class) pairs

__device__ __forceinline__ unsigned mono_key(float s) {
    unsigned b = __float_as_uint(s);
    return (b & 0x80000000u) ? ~b : (b | 0x80000000u);
}
__device__ __forceinline__ float mono_val(unsigned k) {
    return (k & 0x80000000u) ? __uint_as_float(k ^ 0x80000000u) : __uint_as_float(~k);
}
// Correctly-rounded-to-f32 sigmoid via double; matched XLA exactly (absmax 0.0 r1-r4).
__device__ __forceinline__ float sigmoid_f(float x) {
    return (float)(1.0 / (1.0 + exp(-(double)x)));
}

__device__ __forceinline__ unsigned long long shflx64(unsigned long long v, int d) {
    unsigned lo = (unsigned)v, hi = (unsigned)(v >> 32);
    lo = (unsigned)__shfl_xor((int)lo, d, 64);
    hi = (unsigned)__shfl_xor((int)hi, d, 64);
    return ((unsigned long long)hi << 32) | (unsigned long long)lo;
}
__device__ __forceinline__ unsigned long long ce_dir(unsigned long long v, unsigned long long u,
                                                     unsigned idx, unsigned j, unsigned k) {
    bool take_max = (((idx & k) == 0u) == ((idx & j) == 0u));
    bool u_gt = (u > v);
    return (take_max == u_gt) ? u : v;
}

// RetinaNet anchors, levels 3..7, 640x640, xywh. Replicates reference float32 math.
__device__ void anchor_at(int idx, float& ax, float& ay, float& aw, float& ah) {
    int l, li = idx;
    if (idx < 57600)      { l = 0; }
    else if (idx < 72000) { l = 1; li = idx - 57600; }
    else if (idx < 75600) { l = 2; li = idx - 72000; }
    else if (idx < 76500) { l = 3; li = idx - 75600; }
    else                  { l = 4; li = idx - 76500; }
    int stride = 8 << l;
    int fsz = 640 >> (3 + l);
    int cell = li / 9, a = li - cell * 9;
    int cyi = cell / fsz, cxi = cell - cyi * fsz;
    float fst = (float)stride;
    ax = ((float)cxi + 0.5f) * fst;
    ay = ((float)cyi + 0.5f) * fst;
    float side = (float)(stride * 4);
    float area = side * side;
    int ri = a / 3, si = a - ri * 3;
    float ratio = (ri == 0) ? 0.5f : ((ri == 1) ? 1.0f : 2.0f);
    float scl = (si == 0) ? 1.0f
              : ((si == 1) ? 1.25992104989487316476721f
                           : 1.58740105196819947475170564f);
    float h = sqrtf(area / ratio);
    float w = area / h;
    aw = scl * w;
    ah = scl * h;
}

// counters padded to one 64B line each: gcnt[sub*16]
__device__ __forceinline__ void emit_one(int b, unsigned el, float x, unsigned stripe,
                                         unsigned long long* glist, unsigned* gcnt) {
    unsigned anchor = el / 84u;
    unsigned col = el - anchor * 84u;
    int c = (int)col - 4;
    unsigned key = mono_key(sigmoid_f(x));
    unsigned sub = (unsigned)(b * NCLS + c) * NSTRIPE + stripe;
    unsigned pos = atomicAdd(&gcnt[sub << 4], 1u);
    if (pos < SCAP)
        glist[(size_t)sub * SCAP + pos] =
            ((unsigned long long)key << 32) | (unsigned long long)(0xFFFFFFFFu - anchor);
}

// ---------------- Kernel 1: threshold-collect (pure-ILP stream + dense tail) --
// __launch_bounds__(256,4): r2 showed VGPR_Count=28 -> compiler serialized the
// 10 in-flight loads to minimize registers; 128-VGPR budget lets them overlap.
__global__ __launch_bounds__(256, 4) void collect_kernel(const float* __restrict__ pred,
                                                         unsigned long long* __restrict__ glist,
                                                         unsigned* __restrict__ gcnt) {
    __shared__ unsigned pend[512];
    __shared__ unsigned s_p;
    int b = blockIdx.y;
    int tid = threadIdx.x;
    unsigned stripe = (unsigned)blockIdx.x & (NSTRIPE - 1u);
    if (tid == 0) s_p = 0u;
    __syncthreads();
    const float4* p4 = (const float4*)(pred + (size_t)b * EL_PER_IMG);
    unsigned base4 = (unsigned)blockIdx.x * 2560u + (unsigned)tid;

    float4 v[10];
    unsigned fidx[10];
#pragma unroll
    for (int k = 0; k < 10; k++) {
        unsigned f = base4 + (unsigned)k * 256u;
        fidx[k] = f;
        unsigned fc = (f < (unsigned)F4_PER_IMG) ? f : (unsigned)(F4_PER_IMG - 1);
        v[k] = p4[fc];
    }
#pragma unroll
    for (int k = 0; k < 10; k++) {
        unsigned f = fidx[k];
        bool ok = (f < (unsigned)F4_PER_IMG) && (f % 21u != 0u);  // %21==0 => box cols
        float4 w = v[k];
        if (ok && (w.x >= XCUT || w.y >= XCUT || w.z >= XCUT || w.w >= XCUT)) {
#pragma unroll
            for (int j = 0; j < 4; j++) {
                float x = (j == 0) ? w.x : (j == 1) ? w.y : (j == 2) ? w.z : w.w;
                if (x >= XCUT) {
                    unsigned pos = atomicAdd(&s_p, 1u);
                    unsigned el = f * 4u + (unsigned)j;
                    if (pos < 512u) pend[pos] = el;
                    else emit_one(b, el, x, stripe, glist, gcnt);
                }
            }
        }
    }
    __syncthreads();
    unsigned np = s_p; if (np > 512u) np = 512u;
    for (unsigned i = (unsigned)tid; i < np; i += 256u) {
        unsigned el = pend[i];
        float x = pred[(size_t)b * EL_PER_IMG + el];
        emit_one(b, el, x, stripe, glist, gcnt);
    }
}

// parallel suffix (inclusive, from high index down) over 2048 u32 in LDS, 512 thr
__device__ __forceinline__ void suffix_scan_2048(unsigned* h, int tid) {
    for (unsigned off = 1; off < 2048; off <<= 1) {
        unsigned v[4];
#pragma unroll
        for (int q = 0; q < 4; q++) {
            unsigned t = (unsigned)tid + q * 512u;
            v[q] = (t + off < 2048u) ? h[t + off] : 0u;
        }
        __syncthreads();
#pragma unroll
        for (int q = 0; q < 4; q++) h[tid + q * 512] += v[q];
        __syncthreads();
    }
}

// ---------------- Kernel 2a: gather + partition + reg-bitonic + decode --------
// 28 KB LDS -> 5 blocks/CU; all 320 blocks co-resident.
__global__ __launch_bounds__(512) void select_decode_kernel(
        const float* __restrict__ pred, const unsigned long long* __restrict__ glist,
        const unsigned* __restrict__ gcnt,
        float4* __restrict__ g_xyxy, float4* __restrict__ g_xywh,
        float2* __restrict__ g_sa) {
    int bc = blockIdx.x;
    int b = bc / NCLS, c = bc - b * NCLS;
    int tid = threadIdx.x;

    __shared__ unsigned long long clist[2048];   // 16 KB raw gather / fallback scratch
    __shared__ unsigned long long sout[1024];    // 8 KB sorted output; fallback: fhist[2048] u32
    __shared__ unsigned eqbuf[1024];             // 4 KB: fast hist[512] / fallback eqlist[1024]
    __shared__ unsigned scnt[NSTRIPE], soff[NSTRIPE];
    __shared__ unsigned wsum[8];
    __shared__ int s_ok;
    __shared__ unsigned s_total, s_tb, a_ctr, e_ctr, s_fail;
    __shared__ unsigned sh_t, sh_above, s_cnt, s_eq;

    unsigned* hist = eqbuf;                      // 512 bins (fast path)

    const unsigned KCUT = mono_key(sigmoid_f(XCUT));
    const unsigned BASE = KCUT >> 12;            // fast keys in (KCUT, mono(1.0f)]

    if (tid < NSTRIPE)
        scnt[tid] = gcnt[(((unsigned)bc * NSTRIPE + (unsigned)tid) << 4)];
    for (int i = tid; i < 1024; i += 512) sout[i] = 0ull;
    if (tid < 512) hist[tid] = 0u;
    if (tid == 0) { a_ctr = 0u; e_ctr = 0u; s_fail = 0u; }
    __syncthreads();
    if (tid == 0) {
        unsigned o = 0; int ok = 1;
        for (int s = 0; s < NSTRIPE; s++) {
            unsigned cs_ = scnt[s];
            if (cs_ > SCAP) ok = 0;
            soff[s] = o;
            o += (cs_ < SCAP ? cs_ : SCAP);
        }
        s_total = o;
        s_ok = ok && (o >= PREK);
    }
    __syncthreads();

    // gather: 4 fully-independent vector loads per thread (unrollable, all in flight)
#pragma unroll
    for (int q = 0; q < 4; q++) {
        unsigned qq = (unsigned)tid + (unsigned)q * 512u;       // < 2048 = 16*128
        unsigned s = qq >> 7, i = qq & (SCAP - 1u);
        unsigned long long e2 = glist[(size_t)((unsigned)bc * NSTRIPE + s) * SCAP + i];
        unsigned cs_ = scnt[s]; if (cs_ > SCAP) cs_ = SCAP;
        if (i < cs_) {
            clist[soff[s] + i] = e2;
            int bin = (int)((unsigned)(e2 >> 32) >> 12) - (int)BASE;
            bin = bin < 0 ? 0 : (bin > 511 ? 511 : bin);
            atomicAdd(&hist[bin], 1u);
        }
    }
    __syncthreads();

    bool fastb = (s_ok != 0);
    if (fastb) {
        // suffix scan over 512 bins: wave shfl + cross-wave combine
        unsigned vbin = hist[tid];
        int lane = tid & 63, w8 = tid >> 6;
#pragma unroll
        for (int off = 1; off < 64; off <<= 1) {
            unsigned u = (unsigned)__shfl_down((int)vbin, off, 64);
            if (lane + off < 64) vbin += u;
        }
        if (lane == 0) wsum[w8] = vbin;
        __syncthreads();
        if (tid == 0) {
            unsigned acc = 0;
            for (int w = 7; w >= 0; w--) { unsigned t = wsum[w]; wsum[w] = acc; acc += t; }
        }
        __syncthreads();
        vbin += wsum[w8];
        hist[tid] = vbin;          // suffix counts
        __syncthreads();
        unsigned S = vbin, S1 = (tid < 511) ? hist[tid + 1] : 0u;
        if (S >= PREK && S1 < PREK) s_tb = (unsigned)tid;
        __syncthreads();
        unsigned tb = s_tb;
        unsigned total = s_total;
        // recollect: above-set -> sout[0..A), boundary bin -> sout[512..512+eq)
        for (unsigned i = (unsigned)tid; i < total; i += 512u) {
            unsigned long long e2 = clist[i];
            int bin = (int)((unsigned)(e2 >> 32) >> 12) - (int)BASE;
            bin = bin < 0 ? 0 : (bin > 511 ? 511 : bin);
            if ((unsigned)bin > tb) {
                unsigned p = atomicAdd(&a_ctr, 1u);
                sout[p] = e2;                          // p < 512 guaranteed
            } else if ((unsigned)bin == tb) {
                unsigned p = atomicAdd(&e_ctr, 1u);
                if (p < 512u) sout[512u + p] = e2;
                else s_fail = 1u;
            }
        }
        __syncthreads();
        if (s_fail) fastb = false;
    }
    if (fastb) {
        // register bitonic sort of sout[0..1024) descending; idx = 2*tid + e
        unsigned i0 = (unsigned)tid * 2u, i1 = i0 + 1u;
        unsigned long long v0 = sout[i0], v1 = sout[i1];
        for (unsigned k = 2; k <= 1024; k <<= 1) {
            for (unsigned j = k >> 1; j >= 1; j >>= 1) {
                if (j >= 128) {
                    sout[i0] = v0; sout[i1] = v1;
                    __syncthreads();
                    unsigned long long u0 = sout[i0 ^ j], u1 = sout[i1 ^ j];
                    v0 = ce_dir(v0, u0, i0, j, k);
                    v1 = ce_dir(v1, u1, i1, j, k);
                    __syncthreads();
                } else if (j >= 2) {
                    int d = (int)(j >> 1);
                    unsigned long long u0 = shflx64(v0, d), u1 = shflx64(v1, d);
                    v0 = ce_dir(v0, u0, i0, j, k);
                    v1 = ce_dir(v1, u1, i1, j, k);
                } else {
                    bool tm = ((i0 & k) == 0u);
                    unsigned long long mx = v0 > v1 ? v0 : v1;
                    unsigned long long mn = v0 > v1 ? v1 : v0;
                    v0 = tm ? mx : mn; v1 = tm ? mn : mx;
                }
            }
        }
        sout[i0] = v0; sout[i1] = v1;
        __syncthreads();
        unsigned key511 = (unsigned)(sout[511] >> 32);
        fastb = key511 > KCUT;     // proof: every uncollected key <= KCUT
    }

    if (!fastb) {
        // exact 3-level radix-select fallback (never taken on bench input)
        unsigned* fhist = (unsigned*)sout;       // 2048 u32
        unsigned* eqlist = eqbuf;                // 1024 u32
        const float* predc = pred + (size_t)b * NANCH * 84 + 4 + c;
        auto getkey = [&](int i) -> unsigned {
            return mono_key(sigmoid_f(predc[(size_t)i * 84]));
        };
        __syncthreads();
        for (int t = tid; t < 2048; t += 512) fhist[t] = 0u;
        __syncthreads();
        for (int i = tid; i < NANCH; i += 512) atomicAdd(&fhist[getkey(i) >> 21], 1u);
        __syncthreads();
        suffix_scan_2048(fhist, tid);
        unsigned target = PREK;
#pragma unroll
        for (int q = 0; q < 4; q++) {
            int t = tid + q * 512;
            unsigned St = fhist[t], St1 = (t < 2047) ? fhist[t + 1] : 0u;
            if (St >= target && St1 < target) { sh_t = (unsigned)t; sh_above = St1; }
        }
        __syncthreads();
        unsigned t0 = sh_t, above = sh_above;
        __syncthreads();
        for (int t = tid; t < 2048; t += 512) fhist[t] = 0u;
        __syncthreads();
        for (int i = tid; i < NANCH; i += 512) {
            unsigned k = getkey(i);
            if ((k >> 21) == t0) atomicAdd(&fhist[(k >> 10) & 0x7FFu], 1u);
        }
        __syncthreads();
        suffix_scan_2048(fhist, tid);
        target = PREK - above;
#pragma unroll
        for (int q = 0; q < 4; q++) {
            int t = tid + q * 512;
            unsigned St = fhist[t], St1 = (t < 2047) ? fhist[t + 1] : 0u;
            if (St >= target && St1 < target) { sh_t = (unsigned)t; sh_above = St1; }
        }
        __syncthreads();
        unsigned t1 = sh_t; above += sh_above;
        __syncthreads();
        for (int t = tid; t < 2048; t += 512) fhist[t] = 0u;
        __syncthreads();
        unsigned pfx2 = (t0 << 11) | t1;
        for (int i = tid; i < NANCH; i += 512) {
            unsigned k = getkey(i);
            if ((k >> 10) == pfx2) atomicAdd(&fhist[k & 0x3FFu], 1u);
        }
        __syncthreads();
        suffix_scan_2048(fhist, tid);
        target = PREK - above;
#pragma unroll
        for (int q = 0; q < 4; q++) {
            int t = tid + q * 512;
            unsigned St = fhist[t], St1 = (t < 2047) ? fhist[t + 1] : 0u;
            if (St >= target && St1 < target) { sh_t = (unsigned)t; sh_above = St1; }
        }
        __syncthreads();
        unsigned t2 = sh_t; above += sh_above;
        unsigned B = (t0 << 21) | (t1 << 10) | t2;
        unsigned R = PREK - above;
        if (tid == 0) { s_cnt = 0u; s_eq = 0u; }
        __syncthreads();
        for (int i = tid; i < NANCH; i += 512) {
            unsigned k = getkey(i);
            if (k > B) {
                unsigned p = atomicAdd(&s_cnt, 1u);
                clist[p] = ((unsigned long long)k << 32) | (unsigned long long)(0xFFFFFFFFu - (unsigned)i);
            } else if (k == B) {
                unsigned p = atomicAdd(&s_eq, 1u);
                if (p < 1024u) eqlist[p] = (unsigned)i;
            }
        }
        __syncthreads();
        unsigned eqn = s_eq < 1024u ? s_eq : 1024u;
        for (int t = tid; t < 1024; t += 512)
            if ((unsigned)t >= eqn) eqlist[t] = 0xFFFFFFFFu;
        __syncthreads();
        for (unsigned k2 = 2; k2 <= 1024; k2 <<= 1)
            for (unsigned j = k2 >> 1; j > 0; j >>= 1) {
                for (int i = tid; i < 1024; i += 512) {
                    unsigned ixj = (unsigned)i ^ j;
                    if (ixj > (unsigned)i) {
                        unsigned a = eqlist[i], bb = eqlist[ixj];
                        bool asc = (((unsigned)i & k2) == 0u);
                        if (asc ? (a > bb) : (a < bb)) { eqlist[i] = bb; eqlist[ixj] = a; }
                    }
                }
                __syncthreads();
            }
        for (unsigned t = tid; t < R; t += 512) {
            unsigned idxe = eqlist[t];
            clist[above + t] = ((unsigned long long)B << 32) | (unsigned long long)(0xFFFFFFFFu - idxe);
        }
        __syncthreads();
        for (unsigned k2 = 2; k2 <= PREK; k2 <<= 1)
            for (unsigned j = k2 >> 1; j > 0; j >>= 1) {
                unsigned i = (unsigned)tid, ixj = i ^ j;
                if (ixj > i) {
                    unsigned long long a = clist[i], bb = clist[ixj];
                    bool desc = ((i & k2) == 0u);
                    if (desc ? (a < bb) : (a > bb)) { clist[i] = bb; clist[ixj] = a; }
                }
                __syncthreads();
            }
        __syncthreads();
    }

    // ---- decode the 512 sorted candidates -> global (exact reference math) ----
    unsigned long long e = fastb ? sout[tid] : clist[tid];
    unsigned key = (unsigned)(e >> 32);
    unsigned aidx = 0xFFFFFFFFu - (unsigned)(e & 0xFFFFFFFFull);
    float score = mono_val(key);
    const float4 pv = *(const float4*)(pred + ((size_t)b * NANCH + aidx) * 84);
    float ax, ay, aw, ah;
    anchor_at((int)aidx, ax, ay, aw, ah);
    float bx = pv.x * 0.1f, by = pv.y * 0.1f, bw2 = pv.z * 0.2f, bh2 = pv.w * 0.2f;
    float cx = bx * aw + ax, cy = by * ah + ay;
    float w = (float)exp((double)bw2) * aw;
    float h = (float)exp((double)bh2) * ah;
    float x1 = cx - w * 0.5f, y1 = cy - h * 0.5f;
    float x2 = cx + w * 0.5f, y2 = cy + h * 0.5f;
    float area = (x2 - x1) * (y2 - y1);
    size_t gi = (size_t)bc * PREK + (unsigned)tid;
    g_xyxy[gi] = make_float4(x1, y1, x2, y2);
    g_xywh[gi] = make_float4(cx, cy, w, h);
    g_sa[gi]   = make_float2(score, area);
}

// ---------------- Kernel 2b: bitmask NMS + compact -> per-class top-100 -------
// 47 KB LDS -> 3 blocks/CU; all 320 blocks co-resident.
__global__ __launch_bounds__(512) void nms_kernel(
        const float4* __restrict__ g_xyxy, const float4* __restrict__ g_xywh,
        const float2* __restrict__ g_sa,
        float* __restrict__ cls_scores, float* __restrict__ cls_boxes) {
    int bc = blockIdx.x;
    int tid = threadIdx.x;

    __shared__ unsigned rowb[512 * 17];      // 34.8 KB bit rows (17-stride kills conflicts)
    __shared__ float4 sbox[PREK];            // 8 KB
    __shared__ float sarea[PREK];            // 2 KB
    __shared__ int svalid[PREK];             // 2 KB
    __shared__ unsigned keepw[16];
    __shared__ unsigned wsum[8];

    size_t gi = (size_t)bc * PREK + (unsigned)tid;
    float4 bx4 = g_xyxy[gi];
    float4 xywh = g_xywh[gi];
    float2 sa = g_sa[gi];
    float score = sa.x, area = sa.y;
    int validr = (score > CONF_THRF) ? 1 : 0;
    sbox[tid] = bx4;
    sarea[tid] = area;
    svalid[tid] = validr;
    for (int i = tid; i < 512 * 17; i += 512) rowb[i] = 0u;
    __syncthreads();

    // ---- balanced triangular bit-matrix build ----
    int w_ = tid >> 6, lane6 = tid & 63;
    for (int p = w_; p < 36; p += 8) {
        int rw = 0, basep = 0;
        while (basep + (8 - rw) <= p) { basep += 8 - rw; rw++; }
        int ct = rw + (p - basep);
        int r = rw * 64 + lane6;
        float4 br = sbox[r];
        float ar = sarea[r];
        int vr = svalid[r];
        unsigned m0 = 0u, m1 = 0u;
#pragma unroll 8
        for (int jj = 0; jj < 64; jj++) {
            int j = ct * 64 + jj;
            float4 bj = sbox[j];               // uniform j -> LDS broadcast
            float aj = sarea[j];
            float xx1 = fmaxf(br.x, bj.x);
            float yy1 = fmaxf(br.y, bj.y);
            float xx2 = fminf(br.z, bj.z);
            float yy2 = fminf(br.w, bj.w);
            float ww = fmaxf(xx2 - xx1, 0.0f);
            float hh = fmaxf(yy2 - yy1, 0.0f);
            float inter = ww * hh;
            float uni = ar + aj - inter;
            float iou = inter / fmaxf(uni, 1e-8f);   // exact reference arithmetic
            bool sup = (iou > IOU_THRF) && (j > r) && vr;
            if (jj < 32) m0 |= sup ? (1u << jj) : 0u;
            else         m1 |= sup ? (1u << (jj - 32)) : 0u;
        }
        rowb[r * 17 + 2 * ct] = m0;
        rowb[r * 17 + 2 * ct + 1] = m1;
    }
    __syncthreads();

    // ---- resolve: chunked broadcast, 2-VALU dependent chain per step ----
    if (tid < 64) {
        int w16 = tid & 15;
        unsigned kw = 0xFFFFFFFFu;
        for (int cch = 0; cch < 16; cch++) {
            unsigned local = (unsigned)__shfl((int)kw, cch);
            for (int ii = 0; ii < 32; ii++) {
                int i = cch * 32 + ii;
                unsigned rb = rowb[i * 17 + w16];
                unsigned rw2 = rowb[i * 17 + cch];
                if ((local >> ii) & 1u) {
                    local &= ~rw2;
                    kw &= ~rb;
                }
            }
        }
        if (tid < 16) keepw[tid] = kw;
    }
    __syncthreads();

    // ---- ballot compaction -> per-class top-100 ----
    unsigned kbit = (keepw[tid >> 5] >> (tid & 31)) & 1u;
    int kept = (int)kbit & validr;
    unsigned long long bal = __ballot(kept != 0);
    if (lane6 == 0) wsum[w_] = (unsigned)__popcll(bal);
    __syncthreads();
    int rank = 0;
    for (int u = 0; u < w_; u++) rank += (int)wsum[u];
    rank += (int)__popcll(bal & ((1ull << lane6) - 1ull));

    float* cs = cls_scores + (size_t)bc * MAXDET;
    float* cb = cls_boxes + (size_t)bc * MAXDET * 4;
    for (int r = tid; r < MAXDET; r += 512) {
        cs[r] = -1.0f;
        cb[r * 4 + 0] = -1.0f; cb[r * 4 + 1] = -1.0f;
        cb[r * 4 + 2] = -1.0f; cb[r * 4 + 3] = -1.0f;
    }
    __syncthreads();
    if (kept && rank < MAXDET) {
        cs[rank] = score;
        cb[rank * 4 + 0] = xywh.x; cb[rank * 4 + 1] = xywh.y;
        cb[rank * 4 + 2] = xywh.z; cb[rank * 4 + 3] = xywh.w;
    }
}

// ---------------- Kernel 3: per-image top-100 via register bitonic ------------
__global__ __launch_bounds__(1024) void final_topk(const float* __restrict__ cls_scores,
                                                   const float* __restrict__ cls_boxes,
                                                   float* __restrict__ out) {
    int b = blockIdx.x;
    int tid = threadIdx.x;
    __shared__ unsigned long long arr[8192];          // 64 KB staging
    unsigned long long v[8];
    unsigned idx0 = (unsigned)tid * 8u;
#pragma unroll
    for (int e = 0; e < 8; e++) {
        unsigned i = idx0 + (unsigned)e;
        unsigned long long val = 0ull;
        if (i < (unsigned)(NCLS * MAXDET)) {
            float s = cls_scores[(size_t)b * NCLS * MAXDET + i];
            val = ((unsigned long long)mono_key(s) << 32)
                | (unsigned long long)(0xFFFFFFFFu - i);
        }
        v[e] = val;
    }
#pragma unroll 1
    for (unsigned k = 2; k <= 8192; k <<= 1) {
#pragma unroll 1
        for (unsigned j = k >> 1; j >= 1; j >>= 1) {
            if (j >= 512) {
#pragma unroll
                for (int e = 0; e < 8; e++) arr[idx0 + e] = v[e];
                __syncthreads();
#pragma unroll
                for (int e = 0; e < 8; e++) {
                    unsigned idx = idx0 + (unsigned)e;
                    unsigned long long u = arr[idx ^ j];
                    v[e] = ce_dir(v[e], u, idx, j, k);
                }
                __syncthreads();
            } else if (j >= 8) {
                int d = (int)(j >> 3);
#pragma unroll
                for (int e = 0; e < 8; e++) {
                    unsigned idx = idx0 + (unsigned)e;
                    unsigned long long u = shflx64(v[e], d);
                    v[e] = ce_dir(v[e], u, idx, j, k);
                }
            } else {
#pragma unroll
                for (int e = 0; e < 8; e++) {
                    if ((e & (int)j) == 0) {
                        int e2 = e | (int)j;
                        unsigned idx = idx0 + (unsigned)e;
                        bool tm = ((idx & k) == 0u);
                        unsigned long long mx = v[e] > v[e2] ? v[e] : v[e2];
                        unsigned long long mn = v[e] > v[e2] ? v[e2] : v[e];
                        v[e] = tm ? mx : mn;
                        v[e2] = tm ? mn : mx;
                    }
                }
            }
        }
    }
#pragma unroll
    for (int e = 0; e < 8; e++) arr[idx0 + e] = v[e];
    __syncthreads();

    bool vd = false;
    if (tid < MAXDET) {
        unsigned long long e = arr[tid];
        unsigned mk = (unsigned)(e >> 32);
        float s = mono_val(mk);
        unsigned fi = 0xFFFFFFFFu - (unsigned)(e & 0xFFFFFFFFull);
        vd = (s >= CONF_THRF);
        float obx = -1.0f, oby = -1.0f, obw = -1.0f, obh = -1.0f;
        float ofs = -1.0f, ofc = -1.0f;
        if (vd) {
            const float* bp = cls_boxes + ((size_t)b * NCLS * MAXDET + fi) * 4;
            obx = bp[0]; oby = bp[1]; obw = bp[2]; obh = bp[3];
            ofs = s;
            ofc = (float)(fi / MAXDET);
        }
        int o = b * MAXDET + tid;
        out[o * 4 + 0] = obx; out[o * 4 + 1] = oby;
        out[o * 4 + 2] = obw; out[o * 4 + 3] = obh;
        out[NIMG * MAXDET * 4 + o] = ofs;
        out[NIMG * MAXDET * 5 + o] = ofc;
    }
    __syncthreads();
    unsigned long long bal = __ballot(vd);
    if ((tid & 63) == 0) arr[tid >> 6] = bal;
    __syncthreads();
    if (tid == 0) {
        int cnt2 = 0;
        for (int u = 0; u < 16; u++) cnt2 += (int)__popcll(arr[u]);
        out[NIMG * MAXDET * 6 + b] = (float)cnt2;
    }
}

extern "C" void kernel_launch(void* const* d_in, const int* in_sizes, int n_in,
                              void* d_out, int out_size, void* d_ws, size_t ws_size,
                              hipStream_t stream) {
    (void)in_sizes; (void)n_in; (void)out_size; (void)ws_size;
    const float* pred = (const float*)d_in[1];  // d_in[0] = images (only H=W=640 used)
    float* out = (float*)d_out;

    char* base = (char*)d_ws;
    size_t off = 0;
    unsigned* gcnt = (unsigned*)(base + off);                  // 5120 x 64B = 327,680
    off += (size_t)NSUB * 16 * sizeof(unsigned);
    unsigned long long* glist = (unsigned long long*)(base + off);  // 5.24 MB
    off += (size_t)NSUB * SCAP * 8u;
    float4* g_xyxy = (float4*)(base + off);                    // 2.62 MB
    off += (size_t)NBC * PREK * 16u;
    float4* g_xywh = (float4*)(base + off);                    // 2.62 MB
    off += (size_t)NBC * PREK * 16u;
    float2* g_sa = (float2*)(base + off);                      // 1.31 MB
    off += (size_t)NBC * PREK * 8u;
    float* cls_scores = (float*)(base + off);                  // 128 KB
    off += (size_t)NBC * MAXDET * sizeof(float);
    float* cls_boxes = (float*)(base + off);                   // 512 KB

    hipMemsetAsync(gcnt, 0, (size_t)NSUB * 16 * sizeof(unsigned), stream);
    collect_kernel<<<dim3(630, NIMG), 256, 0, stream>>>(pred, glist, gcnt);
    select_decode_kernel<<<NBC, 512, 0, stream>>>(pred, glist, gcnt, g_xyxy, g_xywh, g_sa);
    nms_kernel<<<NBC, 512, 0, stream>>>(g_xyxy, g_xywh, g_sa, cls_scores, cls_boxes);
    final_topk<<<NIMG, 1024, 0, stream>>>(cls_scores, cls_boxes, out);
}

// Round 6
// 281.357 us; speedup vs baseline: 2.6043x; 1.2916x over previous
//
#include <hip/hip_runtime.h>
#include <math.h>

#define NANCH 76725
#define NCLS 80
#define NIMG 4
#define PREK 512
#define MAXDET 100
#define CONF_THRF 0.05f
#define IOU_THRF 0.5f
#define XCUT 2.2f            // logit cut: sigmoid(2.2)=0.90025; 512th-best per class ~0.92
#define NSTRIPE 16           // per-class atomic striping (by blockIdx.x & 15)
#define SCAP 128             // capacity per (class,stripe) sub-list; expected ~67 +/- 8
#define F4_PER_IMG 1611225   // 76725*84/4
#define EL_PER_IMG 6444900   // 76725*84
#define NSUB (NIMG * NCLS * NSTRIPE)   // 5120 sub-lists
#define NBC (NIMG * NCLS)              // 320 (image,class) pairs

__device__ __forceinline__ unsigned mono_key(float s) {
    unsigned b = __float_as_uint(s);
    return (b & 0x80000000u) ? ~b : (b | 0x80000000u);
}
__device__ __forceinline__ float mono_val(unsigned k) {
    return (k & 0x80000000u) ? __uint_as_float(k ^ 0x80000000u) : __uint_as_float(~k);
}
// Correctly-rounded-to-f32 sigmoid via double; matched XLA exactly (absmax 0.0 r1-r5).
__device__ __forceinline__ float sigmoid_f(float x) {
    return (float)(1.0 / (1.0 + exp(-(double)x)));
}

__device__ __forceinline__ unsigned long long shflx64(unsigned long long v, int d) {
    unsigned lo = (unsigned)v, hi = (unsigned)(v >> 32);
    lo = (unsigned)__shfl_xor((int)lo, d, 64);
    hi = (unsigned)__shfl_xor((int)hi, d, 64);
    return ((unsigned long long)hi << 32) | (unsigned long long)lo;
}
__device__ __forceinline__ unsigned long long ce_dir(unsigned long long v, unsigned long long u,
                                                     unsigned idx, unsigned j, unsigned k) {
    bool take_max = (((idx & k) == 0u) == ((idx & j) == 0u));
    bool u_gt = (u > v);
    return (take_max == u_gt) ? u : v;
}

// RetinaNet anchors, levels 3..7, 640x640, xywh. Replicates reference float32 math.
__device__ void anchor_at(int idx, float& ax, float& ay, float& aw, float& ah) {
    int l, li = idx;
    if (idx < 57600)      { l = 0; }
    else if (idx < 72000) { l = 1; li = idx - 57600; }
    else if (idx < 75600) { l = 2; li = idx - 72000; }
    else if (idx < 76500) { l = 3; li = idx - 75600; }
    else                  { l = 4; li = idx - 76500; }
    int stride = 8 << l;
    int fsz = 640 >> (3 + l);
    int cell = li / 9, a = li - cell * 9;
    int cyi = cell / fsz, cxi = cell - cyi * fsz;
    float fst = (float)stride;
    ax = ((float)cxi + 0.5f) * fst;
    ay = ((float)cyi + 0.5f) * fst;
    float side = (float)(stride * 4);
    float area = side * side;
    int ri = a / 3, si = a - ri * 3;
    float ratio = (ri == 0) ? 0.5f : ((ri == 1) ? 1.0f : 2.0f);
    float scl = (si == 0) ? 1.0f
              : ((si == 1) ? 1.25992104989487316476721f
                           : 1.58740105196819947475170564f);
    float h = sqrtf(area / ratio);
    float w = area / h;
    aw = scl * w;
    ah = scl * h;
}

// counters padded to one 64B line each: gcnt[sub*16]
__device__ __forceinline__ void emit_one(int b, unsigned el, float x, unsigned stripe,
                                         unsigned long long* glist, unsigned* gcnt) {
    unsigned anchor = el / 84u;
    unsigned col = el - anchor * 84u;
    int c = (int)col - 4;
    unsigned key = mono_key(sigmoid_f(x));
    unsigned sub = (unsigned)(b * NCLS + c) * NSTRIPE + stripe;
    unsigned pos = atomicAdd(&gcnt[sub << 4], 1u);
    if (pos < SCAP)
        glist[(size_t)sub * SCAP + pos] =
            ((unsigned long long)key << 32) | (unsigned long long)(0xFFFFFFFFu - anchor);
}

// ---------------- Kernel 1: threshold-collect (pure-ILP stream + dense tail) --
__global__ __launch_bounds__(256, 4) void collect_kernel(const float* __restrict__ pred,
                                                         unsigned long long* __restrict__ glist,
                                                         unsigned* __restrict__ gcnt) {
    __shared__ unsigned pend[512];
    __shared__ unsigned s_p;
    int b = blockIdx.y;
    int tid = threadIdx.x;
    unsigned stripe = (unsigned)blockIdx.x & (NSTRIPE - 1u);
    if (tid == 0) s_p = 0u;
    __syncthreads();
    const float4* p4 = (const float4*)(pred + (size_t)b * EL_PER_IMG);
    unsigned base4 = (unsigned)blockIdx.x * 2560u + (unsigned)tid;

    float4 v[10];
    unsigned fidx[10];
#pragma unroll
    for (int k = 0; k < 10; k++) {
        unsigned f = base4 + (unsigned)k * 256u;
        fidx[k] = f;
        unsigned fc = (f < (unsigned)F4_PER_IMG) ? f : (unsigned)(F4_PER_IMG - 1);
        v[k] = p4[fc];
    }
#pragma unroll
    for (int k = 0; k < 10; k++) {
        unsigned f = fidx[k];
        bool ok = (f < (unsigned)F4_PER_IMG) && (f % 21u != 0u);  // %21==0 => box cols
        float4 w = v[k];
        if (ok && (w.x >= XCUT || w.y >= XCUT || w.z >= XCUT || w.w >= XCUT)) {
#pragma unroll
            for (int j = 0; j < 4; j++) {
                float x = (j == 0) ? w.x : (j == 1) ? w.y : (j == 2) ? w.z : w.w;
                if (x >= XCUT) {
                    unsigned pos = atomicAdd(&s_p, 1u);
                    unsigned el = f * 4u + (unsigned)j;
                    if (pos < 512u) pend[pos] = el;
                    else emit_one(b, el, x, stripe, glist, gcnt);
                }
            }
        }
    }
    __syncthreads();
    unsigned np = s_p; if (np > 512u) np = 512u;
    for (unsigned i = (unsigned)tid; i < np; i += 256u) {
        unsigned el = pend[i];
        float x = pred[(size_t)b * EL_PER_IMG + el];
        emit_one(b, el, x, stripe, glist, gcnt);
    }
}

// parallel suffix (inclusive, from high index down) over 2048 u32 in LDS, 512 thr
__device__ __forceinline__ void suffix_scan_2048(unsigned* h, int tid) {
    for (unsigned off = 1; off < 2048; off <<= 1) {
        unsigned v[4];
#pragma unroll
        for (int q = 0; q < 4; q++) {
            unsigned t = (unsigned)tid + q * 512u;
            v[q] = (t + off < 2048u) ? h[t + off] : 0u;
        }
        __syncthreads();
#pragma unroll
        for (int q = 0; q < 4; q++) h[tid + q * 512] += v[q];
        __syncthreads();
    }
}

// ---------------- Kernel 2a: gather + partition + reg-bitonic + decode --------
__global__ __launch_bounds__(512) void select_decode_kernel(
        const float* __restrict__ pred, const unsigned long long* __restrict__ glist,
        const unsigned* __restrict__ gcnt,
        float4* __restrict__ g_xyxy, float4* __restrict__ g_xywh,
        float2* __restrict__ g_sa) {
    int bc = blockIdx.x;
    int b = bc / NCLS, c = bc - b * NCLS;
    int tid = threadIdx.x;

    __shared__ unsigned long long clist[2048];   // 16 KB raw gather / fallback scratch
    __shared__ unsigned long long sout[1024];    // 8 KB sorted output; fallback: fhist[2048] u32
    __shared__ unsigned eqbuf[1024];             // 4 KB: fast hist[512] / fallback eqlist[1024]
    __shared__ unsigned scnt[NSTRIPE], soff[NSTRIPE];
    __shared__ unsigned wsum[8];
    __shared__ int s_ok;
    __shared__ unsigned s_total, s_tb, a_ctr, e_ctr, s_fail;
    __shared__ unsigned sh_t, sh_above, s_cnt, s_eq;

    unsigned* hist = eqbuf;                      // 512 bins (fast path)

    const unsigned KCUT = mono_key(sigmoid_f(XCUT));
    const unsigned BASE = KCUT >> 12;            // fast keys in (KCUT, mono(1.0f)]

    if (tid < NSTRIPE)
        scnt[tid] = gcnt[(((unsigned)bc * NSTRIPE + (unsigned)tid) << 4)];
    for (int i = tid; i < 1024; i += 512) sout[i] = 0ull;
    if (tid < 512) hist[tid] = 0u;
    if (tid == 0) { a_ctr = 0u; e_ctr = 0u; s_fail = 0u; }
    __syncthreads();
    if (tid == 0) {
        unsigned o = 0; int ok = 1;
        for (int s = 0; s < NSTRIPE; s++) {
            unsigned cs_ = scnt[s];
            if (cs_ > SCAP) ok = 0;
            soff[s] = o;
            o += (cs_ < SCAP ? cs_ : SCAP);
        }
        s_total = o;
        s_ok = ok && (o >= PREK);
    }
    __syncthreads();

    // gather: 4 fully-independent vector loads per thread
#pragma unroll
    for (int q = 0; q < 4; q++) {
        unsigned qq = (unsigned)tid + (unsigned)q * 512u;       // < 2048 = 16*128
        unsigned s = qq >> 7, i = qq & (SCAP - 1u);
        unsigned long long e2 = glist[(size_t)((unsigned)bc * NSTRIPE + s) * SCAP + i];
        unsigned cs_ = scnt[s]; if (cs_ > SCAP) cs_ = SCAP;
        if (i < cs_) {
            clist[soff[s] + i] = e2;
            int bin = (int)((unsigned)(e2 >> 32) >> 12) - (int)BASE;
            bin = bin < 0 ? 0 : (bin > 511 ? 511 : bin);
            atomicAdd(&hist[bin], 1u);
        }
    }
    __syncthreads();

    bool fastb = (s_ok != 0);
    if (fastb) {
        unsigned vbin = hist[tid];
        int lane = tid & 63, w8 = tid >> 6;
#pragma unroll
        for (int off = 1; off < 64; off <<= 1) {
            unsigned u = (unsigned)__shfl_down((int)vbin, off, 64);
            if (lane + off < 64) vbin += u;
        }
        if (lane == 0) wsum[w8] = vbin;
        __syncthreads();
        if (tid == 0) {
            unsigned acc = 0;
            for (int w = 7; w >= 0; w--) { unsigned t = wsum[w]; wsum[w] = acc; acc += t; }
        }
        __syncthreads();
        vbin += wsum[w8];
        hist[tid] = vbin;          // suffix counts
        __syncthreads();
        unsigned S = vbin, S1 = (tid < 511) ? hist[tid + 1] : 0u;
        if (S >= PREK && S1 < PREK) s_tb = (unsigned)tid;
        __syncthreads();
        unsigned tb = s_tb;
        unsigned total = s_total;
        for (unsigned i = (unsigned)tid; i < total; i += 512u) {
            unsigned long long e2 = clist[i];
            int bin = (int)((unsigned)(e2 >> 32) >> 12) - (int)BASE;
            bin = bin < 0 ? 0 : (bin > 511 ? 511 : bin);
            if ((unsigned)bin > tb) {
                unsigned p = atomicAdd(&a_ctr, 1u);
                sout[p] = e2;
            } else if ((unsigned)bin == tb) {
                unsigned p = atomicAdd(&e_ctr, 1u);
                if (p < 512u) sout[512u + p] = e2;
                else s_fail = 1u;
            }
        }
        __syncthreads();
        if (s_fail) fastb = false;
    }
    if (fastb) {
        unsigned i0 = (unsigned)tid * 2u, i1 = i0 + 1u;
        unsigned long long v0 = sout[i0], v1 = sout[i1];
        for (unsigned k = 2; k <= 1024; k <<= 1) {
            for (unsigned j = k >> 1; j >= 1; j >>= 1) {
                if (j >= 128) {
                    sout[i0] = v0; sout[i1] = v1;
                    __syncthreads();
                    unsigned long long u0 = sout[i0 ^ j], u1 = sout[i1 ^ j];
                    v0 = ce_dir(v0, u0, i0, j, k);
                    v1 = ce_dir(v1, u1, i1, j, k);
                    __syncthreads();
                } else if (j >= 2) {
                    int d = (int)(j >> 1);
                    unsigned long long u0 = shflx64(v0, d), u1 = shflx64(v1, d);
                    v0 = ce_dir(v0, u0, i0, j, k);
                    v1 = ce_dir(v1, u1, i1, j, k);
                } else {
                    bool tm = ((i0 & k) == 0u);
                    unsigned long long mx = v0 > v1 ? v0 : v1;
                    unsigned long long mn = v0 > v1 ? v1 : v0;
                    v0 = tm ? mx : mn; v1 = tm ? mn : mx;
                }
            }
        }
        sout[i0] = v0; sout[i1] = v1;
        __syncthreads();
        unsigned key511 = (unsigned)(sout[511] >> 32);
        fastb = key511 > KCUT;     // proof: every uncollected key <= KCUT
    }

    if (!fastb) {
        // exact 3-level radix-select fallback (never taken on bench input)
        unsigned* fhist = (unsigned*)sout;       // 2048 u32
        unsigned* eqlist = eqbuf;                // 1024 u32
        const float* predc = pred + (size_t)b * NANCH * 84 + 4 + c;
        auto getkey = [&](int i) -> unsigned {
            return mono_key(sigmoid_f(predc[(size_t)i * 84]));
        };
        __syncthreads();
        for (int t = tid; t < 2048; t += 512) fhist[t] = 0u;
        __syncthreads();
        for (int i = tid; i < NANCH; i += 512) atomicAdd(&fhist[getkey(i) >> 21], 1u);
        __syncthreads();
        suffix_scan_2048(fhist, tid);
        unsigned target = PREK;
#pragma unroll
        for (int q = 0; q < 4; q++) {
            int t = tid + q * 512;
            unsigned St = fhist[t], St1 = (t < 2047) ? fhist[t + 1] : 0u;
            if (St >= target && St1 < target) { sh_t = (unsigned)t; sh_above = St1; }
        }
        __syncthreads();
        unsigned t0 = sh_t, above = sh_above;
        __syncthreads();
        for (int t = tid; t < 2048; t += 512) fhist[t] = 0u;
        __syncthreads();
        for (int i = tid; i < NANCH; i += 512) {
            unsigned k = getkey(i);
            if ((k >> 21) == t0) atomicAdd(&fhist[(k >> 10) & 0x7FFu], 1u);
        }
        __syncthreads();
        suffix_scan_2048(fhist, tid);
        target = PREK - above;
#pragma unroll
        for (int q = 0; q < 4; q++) {
            int t = tid + q * 512;
            unsigned St = fhist[t], St1 = (t < 2047) ? fhist[t + 1] : 0u;
            if (St >= target && St1 < target) { sh_t = (unsigned)t; sh_above = St1; }
        }
        __syncthreads();
        unsigned t1 = sh_t; above += sh_above;
        __syncthreads();
        for (int t = tid; t < 2048; t += 512) fhist[t] = 0u;
        __syncthreads();
        unsigned pfx2 = (t0 << 11) | t1;
        for (int i = tid; i < NANCH; i += 512) {
            unsigned k = getkey(i);
            if ((k >> 10) == pfx2) atomicAdd(&fhist[k & 0x3FFu], 1u);
        }
        __syncthreads();
        suffix_scan_2048(fhist, tid);
        target = PREK - above;
#pragma unroll
        for (int q = 0; q < 4; q++) {
            int t = tid + q * 512;
            unsigned St = fhist[t], St1 = (t < 2047) ? fhist[t + 1] : 0u;
            if (St >= target && St1 < target) { sh_t = (unsigned)t; sh_above = St1; }
        }
        __syncthreads();
        unsigned t2 = sh_t; above += sh_above;
        unsigned B = (t0 << 21) | (t1 << 10) | t2;
        unsigned R = PREK - above;
        if (tid == 0) { s_cnt = 0u; s_eq = 0u; }
        __syncthreads();
        for (int i = tid; i < NANCH; i += 512) {
            unsigned k = getkey(i);
            if (k > B) {
                unsigned p = atomicAdd(&s_cnt, 1u);
                clist[p] = ((unsigned long long)k << 32) | (unsigned long long)(0xFFFFFFFFu - (unsigned)i);
            } else if (k == B) {
                unsigned p = atomicAdd(&s_eq, 1u);
                if (p < 1024u) eqlist[p] = (unsigned)i;
            }
        }
        __syncthreads();
        unsigned eqn = s_eq < 1024u ? s_eq : 1024u;
        for (int t = tid; t < 1024; t += 512)
            if ((unsigned)t >= eqn) eqlist[t] = 0xFFFFFFFFu;
        __syncthreads();
        for (unsigned k2 = 2; k2 <= 1024; k2 <<= 1)
            for (unsigned j = k2 >> 1; j > 0; j >>= 1) {
                for (int i = tid; i < 1024; i += 512) {
                    unsigned ixj = (unsigned)i ^ j;
                    if (ixj > (unsigned)i) {
                        unsigned a = eqlist[i], bb = eqlist[ixj];
                        bool asc = (((unsigned)i & k2) == 0u);
                        if (asc ? (a > bb) : (a < bb)) { eqlist[i] = bb; eqlist[ixj] = a; }
                    }
                }
                __syncthreads();
            }
        for (unsigned t = tid; t < R; t += 512) {
            unsigned idxe = eqlist[t];
            clist[above + t] = ((unsigned long long)B << 32) | (unsigned long long)(0xFFFFFFFFu - idxe);
        }
        __syncthreads();
        for (unsigned k2 = 2; k2 <= PREK; k2 <<= 1)
            for (unsigned j = k2 >> 1; j > 0; j >>= 1) {
                unsigned i = (unsigned)tid, ixj = i ^ j;
                if (ixj > i) {
                    unsigned long long a = clist[i], bb = clist[ixj];
                    bool desc = ((i & k2) == 0u);
                    if (desc ? (a < bb) : (a > bb)) { clist[i] = bb; clist[ixj] = a; }
                }
                __syncthreads();
            }
        __syncthreads();
    }

    // ---- decode the 512 sorted candidates -> global (exact reference math) ----
    unsigned long long e = fastb ? sout[tid] : clist[tid];
    unsigned key = (unsigned)(e >> 32);
    unsigned aidx = 0xFFFFFFFFu - (unsigned)(e & 0xFFFFFFFFull);
    float score = mono_val(key);
    const float4 pv = *(const float4*)(pred + ((size_t)b * NANCH + aidx) * 84);
    float ax, ay, aw, ah;
    anchor_at((int)aidx, ax, ay, aw, ah);
    float bx = pv.x * 0.1f, by = pv.y * 0.1f, bw2 = pv.z * 0.2f, bh2 = pv.w * 0.2f;
    float cx = bx * aw + ax, cy = by * ah + ay;
    float w = (float)exp((double)bw2) * aw;
    float h = (float)exp((double)bh2) * ah;
    float x1 = cx - w * 0.5f, y1 = cy - h * 0.5f;
    float x2 = cx + w * 0.5f, y2 = cy + h * 0.5f;
    float area = (x2 - x1) * (y2 - y1);
    size_t gi = (size_t)bc * PREK + (unsigned)tid;
    g_xyxy[gi] = make_float4(x1, y1, x2, y2);
    g_xywh[gi] = make_float4(cx, cy, w, h);
    g_sa[gi]   = make_float2(score, area);
}

// ---------------- Kernel 2b: ADAPTIVE chunked bitmask NMS ---------------------
// Output = first 100 kept boxes. keep[i] for i<=R (R = idx of 100th kept) only
// depends on pairs within [0,R]; rows beyond R can't affect the output (their
// compaction rank >= 100). So build/resolve 128 rows at a time and stop once
// kept>=100 — statistically chunk 0 suffices (3 of 36 tiles = 8% of the IoUs).
__global__ __launch_bounds__(512) void nms_kernel(
        const float4* __restrict__ g_xyxy, const float4* __restrict__ g_xywh,
        const float2* __restrict__ g_sa,
        float* __restrict__ cls_scores, float* __restrict__ cls_boxes) {
    int bc = blockIdx.x;
    int tid = threadIdx.x;

    __shared__ unsigned rowb[512 * 17];      // 34.8 KB bit rows (17-stride)
    __shared__ float4 sbox[PREK];            // 8 KB
    __shared__ float sarea[PREK];            // 2 KB
    __shared__ int svalid[PREK];             // 2 KB
    __shared__ unsigned keepw[16];
    __shared__ unsigned svalw[16];
    __shared__ unsigned wsum[8];
    __shared__ unsigned s_kept;

    size_t gi = (size_t)bc * PREK + (unsigned)tid;
    float4 bx4 = g_xyxy[gi];
    float4 xywh = g_xywh[gi];
    float2 sa = g_sa[gi];
    float score = sa.x, area = sa.y;
    int validr = (score > CONF_THRF) ? 1 : 0;
    sbox[tid] = bx4;
    sarea[tid] = area;
    svalid[tid] = validr;
    for (int i = tid; i < 512 * 17; i += 512) rowb[i] = 0u;   // unbuilt cols read as 0
    int w_ = tid >> 6, lane6 = tid & 63;
    unsigned long long vbal = __ballot(validr != 0);
    if (lane6 == 0) {
        svalw[2 * w_] = (unsigned)vbal;
        svalw[2 * w_ + 1] = (unsigned)(vbal >> 32);
    }
    if (tid < 16) keepw[tid] = 0xFFFFFFFFu;
    if (tid == 0) s_kept = 0u;
    __syncthreads();

    for (int c = 0; c < 4; c++) {
        // ---- build chunk c: column-tiles {2c, 2c+1}, rows 0..128(c+1) (rt<=ct) ----
        int ntiles = 4 * c + 3;
        for (int p = w_; p < ntiles; p += 8) {
            int fct = 2 * c + 1;                 // tiles in column-tile 2c
            int ct = (p < fct) ? 2 * c : 2 * c + 1;
            int rt = (p < fct) ? p : p - fct;
            int r = rt * 64 + lane6;
            float4 br = sbox[r];
            float ar = sarea[r];
            int vr = svalid[r];
            unsigned m0 = 0u, m1 = 0u;
#pragma unroll 8
            for (int jj = 0; jj < 64; jj++) {
                int j = ct * 64 + jj;
                float4 bj = sbox[j];             // uniform j -> LDS broadcast
                float aj = sarea[j];
                float xx1 = fmaxf(br.x, bj.x);
                float yy1 = fmaxf(br.y, bj.y);
                float xx2 = fminf(br.z, bj.z);
                float yy2 = fminf(br.w, bj.w);
                float ww = fmaxf(xx2 - xx1, 0.0f);
                float hh = fmaxf(yy2 - yy1, 0.0f);
                float inter = ww * hh;
                float uni = ar + aj - inter;
                float iou = inter / fmaxf(uni, 1e-8f);   // exact reference arithmetic
                bool sup = (iou > IOU_THRF) && (j > r) && vr;
                if (jj < 32) m0 |= sup ? (1u << jj) : 0u;
                else         m1 |= sup ? (1u << (jj - 32)) : 0u;
            }
            rowb[r * 17 + 2 * ct] = m0;
            rowb[r * 17 + 2 * ct + 1] = m1;
        }
        __syncthreads();

        // ---- resolve chunk c on wave 0 ----
        if (tid < 64) {
            int w16 = tid & 15;
            unsigned kw = keepw[w16];
            if (c > 0) {
                // apply suppression of earlier kept rows onto the 4 new words
                unsigned a0 = 0u, a1 = 0u, a2 = 0u, a3 = 0u;
                for (int i = tid; i < 128 * c; i += 64) {
                    bool ki = (keepw[i >> 5] >> (i & 31)) & 1u;
                    if (ki) {
                        a0 |= rowb[i * 17 + 4 * c + 0];
                        a1 |= rowb[i * 17 + 4 * c + 1];
                        a2 |= rowb[i * 17 + 4 * c + 2];
                        a3 |= rowb[i * 17 + 4 * c + 3];
                    }
                }
#pragma unroll
                for (int d = 1; d < 64; d <<= 1) {
                    a0 |= (unsigned)__shfl_xor((int)a0, d, 64);
                    a1 |= (unsigned)__shfl_xor((int)a1, d, 64);
                    a2 |= (unsigned)__shfl_xor((int)a2, d, 64);
                    a3 |= (unsigned)__shfl_xor((int)a3, d, 64);
                }
                if (w16 == 4 * c + 0) kw &= ~a0;
                if (w16 == 4 * c + 1) kw &= ~a1;
                if (w16 == 4 * c + 2) kw &= ~a2;
                if (w16 == 4 * c + 3) kw &= ~a3;
            }
            // sequential over the 128 new rows (4 word-chunks of 32)
            for (int cch = 4 * c; cch < 4 * c + 4; cch++) {
                unsigned local = (unsigned)__shfl((int)kw, cch);
                for (int ii = 0; ii < 32; ii++) {
                    int i = cch * 32 + ii;
                    unsigned rb = rowb[i * 17 + w16];
                    unsigned rloc = rowb[i * 17 + cch];
                    if ((local >> ii) & 1u) {    // invalid rows have all-zero bits
                        local &= ~rloc;
                        kw &= ~rb;
                    }
                }
            }
            if (tid < 16) keepw[w16] = kw;
            // count kept & valid among processed words [0, 4(c+1))
            unsigned cntv = (tid < 16 && w16 < 4 * (c + 1))
                          ? (unsigned)__popc(kw & svalw[w16]) : 0u;
#pragma unroll
            for (int d = 1; d < 64; d <<= 1) cntv += (unsigned)__shfl_xor((int)cntv, d, 64);
            if (tid == 0) s_kept = cntv;
        }
        __syncthreads();
        if (s_kept >= MAXDET) break;             // uniform: output can't change further
    }

    // ---- ballot compaction -> per-class top-100 ----
    // rows never resolved keep bit=1, but their rank >= s_kept >= 100 -> discarded
    unsigned kbit = (keepw[tid >> 5] >> (tid & 31)) & 1u;
    int kept = (int)kbit & validr;
    unsigned long long bal = __ballot(kept != 0);
    if (lane6 == 0) wsum[w_] = (unsigned)__popcll(bal);
    __syncthreads();
    int rank = 0;
    for (int u = 0; u < w_; u++) rank += (int)wsum[u];
    rank += (int)__popcll(bal & ((1ull << lane6) - 1ull));

    float* cs = cls_scores + (size_t)bc * MAXDET;
    float* cb = cls_boxes + (size_t)bc * MAXDET * 4;
    for (int r = tid; r < MAXDET; r += 512) {
        cs[r] = -1.0f;
        cb[r * 4 + 0] = -1.0f; cb[r * 4 + 1] = -1.0f;
        cb[r * 4 + 2] = -1.0f; cb[r * 4 + 3] = -1.0f;
    }
    __syncthreads();
    if (kept && rank < MAXDET) {
        cs[rank] = score;
        cb[rank * 4 + 0] = xywh.x; cb[rank * 4 + 1] = xywh.y;
        cb[rank * 4 + 2] = xywh.z; cb[rank * 4 + 3] = xywh.w;
    }
}

// ---------------- Kernel 3: per-image top-100 via register bitonic ------------
__global__ __launch_bounds__(1024) void final_topk(const float* __restrict__ cls_scores,
                                                   const float* __restrict__ cls_boxes,
                                                   float* __restrict__ out) {
    int b = blockIdx.x;
    int tid = threadIdx.x;
    __shared__ unsigned long long arr[8192];          // 64 KB staging
    unsigned long long v[8];
    unsigned idx0 = (unsigned)tid * 8u;
#pragma unroll
    for (int e = 0; e < 8; e++) {
        unsigned i = idx0 + (unsigned)e;
        unsigned long long val = 0ull;
        if (i < (unsigned)(NCLS * MAXDET)) {
            float s = cls_scores[(size_t)b * NCLS * MAXDET + i];
            val = ((unsigned long long)mono_key(s) << 32)
                | (unsigned long long)(0xFFFFFFFFu - i);
        }
        v[e] = val;
    }
#pragma unroll 1
    for (unsigned k = 2; k <= 8192; k <<= 1) {
#pragma unroll 1
        for (unsigned j = k >> 1; j >= 1; j >>= 1) {
            if (j >= 512) {
#pragma unroll
                for (int e = 0; e < 8; e++) arr[idx0 + e] = v[e];
                __syncthreads();
#pragma unroll
                for (int e = 0; e < 8; e++) {
                    unsigned idx = idx0 + (unsigned)e;
                    unsigned long long u = arr[idx ^ j];
                    v[e] = ce_dir(v[e], u, idx, j, k);
                }
                __syncthreads();
            } else if (j >= 8) {
                int d = (int)(j >> 3);
#pragma unroll
                for (int e = 0; e < 8; e++) {
                    unsigned idx = idx0 + (unsigned)e;
                    unsigned long long u = shflx64(v[e], d);
                    v[e] = ce_dir(v[e], u, idx, j, k);
                }
            } else {
#pragma unroll
                for (int e = 0; e < 8; e++) {
                    if ((e & (int)j) == 0) {
                        int e2 = e | (int)j;
                        unsigned idx = idx0 + (unsigned)e;
                        bool tm = ((idx & k) == 0u);
                        unsigned long long mx = v[e] > v[e2] ? v[e] : v[e2];
                        unsigned long long mn = v[e] > v[e2] ? v[e2] : v[e];
                        v[e] = tm ? mx : mn;
                        v[e2] = tm ? mn : mx;
                    }
                }
            }
        }
    }
#pragma unroll
    for (int e = 0; e < 8; e++) arr[idx0 + e] = v[e];
    __syncthreads();

    bool vd = false;
    if (tid < MAXDET) {
        unsigned long long e = arr[tid];
        unsigned mk = (unsigned)(e >> 32);
        float s = mono_val(mk);
        unsigned fi = 0xFFFFFFFFu - (unsigned)(e & 0xFFFFFFFFull);
        vd = (s >= CONF_THRF);
        float obx = -1.0f, oby = -1.0f, obw = -1.0f, obh = -1.0f;
        float ofs = -1.0f, ofc = -1.0f;
        if (vd) {
            const float* bp = cls_boxes + ((size_t)b * NCLS * MAXDET + fi) * 4;
            obx = bp[0]; oby = bp[1]; obw = bp[2]; obh = bp[3];
            ofs = s;
            ofc = (float)(fi / MAXDET);
        }
        int o = b * MAXDET + tid;
        out[o * 4 + 0] = obx; out[o * 4 + 1] = oby;
        out[o * 4 + 2] = obw; out[o * 4 + 3] = obh;
        out[NIMG * MAXDET * 4 + o] = ofs;
        out[NIMG * MAXDET * 5 + o] = ofc;
    }
    __syncthreads();
    unsigned long long bal = __ballot(vd);
    if ((tid & 63) == 0) arr[tid >> 6] = bal;
    __syncthreads();
    if (tid == 0) {
        int cnt2 = 0;
        for (int u = 0; u < 16; u++) cnt2 += (int)__popcll(arr[u]);
        out[NIMG * MAXDET * 6 + b] = (float)cnt2;
    }
}

extern "C" void kernel_launch(void* const* d_in, const int* in_sizes, int n_in,
                              void* d_out, int out_size, void* d_ws, size_t ws_size,
                              hipStream_t stream) {
    (void)in_sizes; (void)n_in; (void)out_size; (void)ws_size;
    const float* pred = (const float*)d_in[1];  // d_in[0] = images (only H=W=640 used)
    float* out = (float*)d_out;

    char* base = (char*)d_ws;
    size_t off = 0;
    unsigned* gcnt = (unsigned*)(base + off);                  // 5120 x 64B = 327,680
    off += (size_t)NSUB * 16 * sizeof(unsigned);
    unsigned long long* glist = (unsigned long long*)(base + off);  // 5.24 MB
    off += (size_t)NSUB * SCAP * 8u;
    float4* g_xyxy = (float4*)(base + off);                    // 2.62 MB
    off += (size_t)NBC * PREK * 16u;
    float4* g_xywh = (float4*)(base + off);                    // 2.62 MB
    off += (size_t)NBC * PREK * 16u;
    float2* g_sa = (float2*)(base + off);                      // 1.31 MB
    off += (size_t)NBC * PREK * 8u;
    float* cls_scores = (float*)(base + off);                  // 128 KB
    off += (size_t)NBC * MAXDET * sizeof(float);
    float* cls_boxes = (float*)(base + off);                   // 512 KB

    hipMemsetAsync(gcnt, 0, (size_t)NSUB * 16 * sizeof(unsigned), stream);
    collect_kernel<<<dim3(630, NIMG), 256, 0, stream>>>(pred, glist, gcnt);
    select_decode_kernel<<<NBC, 512, 0, stream>>>(pred, glist, gcnt, g_xyxy, g_xywh, g_sa);
    nms_kernel<<<NBC, 512, 0, stream>>>(g_xyxy, g_xywh, g_sa, cls_scores, cls_boxes);
    final_topk<<<NIMG, 1024, 0, stream>>>(cls_scores, cls_boxes, out);
}

// Round 7
// 225.715 us; speedup vs baseline: 3.2462x; 1.2465x over previous
//
#include <hip/hip_runtime.h>
#include <math.h>

#define NANCH 76725
#define NCLS 80
#define NIMG 4
#define PREK 512
#define MAXDET 100
#define CONF_THRF 0.05f
#define IOU_THRF 0.5f
#define XCUT 2.2f            // logit cut: sigmoid(2.2)=0.90025; 512th-best per class ~0.92
#define NSTRIPE 16           // per-class atomic striping (by blockIdx.x & 15)
#define SCAP 128             // capacity per (class,stripe) sub-list; expected ~67 +/- 8
#define F4_PER_IMG 1611225   // 76725*84/4
#define EL_PER_IMG 6444900   // 76725*84
#define NSUB (NIMG * NCLS * NSTRIPE)   // 5120 sub-lists
#define NBC (NIMG * NCLS)              // 320 (image,class) pairs

__device__ __forceinline__ unsigned mono_key(float s) {
    unsigned b = __float_as_uint(s);
    return (b & 0x80000000u) ? ~b : (b | 0x80000000u);
}
__device__ __forceinline__ float mono_val(unsigned k) {
    return (k & 0x80000000u) ? __uint_as_float(k ^ 0x80000000u) : __uint_as_float(~k);
}
// Correctly-rounded-to-f32 sigmoid via double; matched XLA exactly (absmax 0.0 r1-r6).
__device__ __forceinline__ float sigmoid_f(float x) {
    return (float)(1.0 / (1.0 + exp(-(double)x)));
}

__device__ __forceinline__ unsigned long long shflx64(unsigned long long v, int d) {
    unsigned lo = (unsigned)v, hi = (unsigned)(v >> 32);
    lo = (unsigned)__shfl_xor((int)lo, d, 64);
    hi = (unsigned)__shfl_xor((int)hi, d, 64);
    return ((unsigned long long)hi << 32) | (unsigned long long)lo;
}
__device__ __forceinline__ unsigned long long ce_dir(unsigned long long v, unsigned long long u,
                                                     unsigned idx, unsigned j, unsigned k) {
    bool take_max = (((idx & k) == 0u) == ((idx & j) == 0u));
    bool u_gt = (u > v);
    return (take_max == u_gt) ? u : v;
}

// RetinaNet anchors, levels 3..7, 640x640, xywh. Replicates reference float32 math.
__device__ void anchor_at(int idx, float& ax, float& ay, float& aw, float& ah) {
    int l, li = idx;
    if (idx < 57600)      { l = 0; }
    else if (idx < 72000) { l = 1; li = idx - 57600; }
    else if (idx < 75600) { l = 2; li = idx - 72000; }
    else if (idx < 76500) { l = 3; li = idx - 75600; }
    else                  { l = 4; li = idx - 76500; }
    int stride = 8 << l;
    int fsz = 640 >> (3 + l);
    int cell = li / 9, a = li - cell * 9;
    int cyi = cell / fsz, cxi = cell - cyi * fsz;
    float fst = (float)stride;
    ax = ((float)cxi + 0.5f) * fst;
    ay = ((float)cyi + 0.5f) * fst;
    float side = (float)(stride * 4);
    float area = side * side;
    int ri = a / 3, si = a - ri * 3;
    float ratio = (ri == 0) ? 0.5f : ((ri == 1) ? 1.0f : 2.0f);
    float scl = (si == 0) ? 1.0f
              : ((si == 1) ? 1.25992104989487316476721f
                           : 1.58740105196819947475170564f);
    float h = sqrtf(area / ratio);
    float w = area / h;
    aw = scl * w;
    ah = scl * h;
}

// counters padded to one 64B line each: gcnt[sub*16]
__device__ __forceinline__ void emit_one(int b, unsigned el, float x, unsigned stripe,
                                         unsigned long long* glist, unsigned* gcnt) {
    unsigned anchor = el / 84u;
    unsigned col = el - anchor * 84u;
    int c = (int)col - 4;
    unsigned key = mono_key(sigmoid_f(x));
    unsigned sub = (unsigned)(b * NCLS + c) * NSTRIPE + stripe;
    unsigned pos = atomicAdd(&gcnt[sub << 4], 1u);
    if (pos < SCAP)
        glist[(size_t)sub * SCAP + pos] =
            ((unsigned long long)key << 32) | (unsigned long long)(0xFFFFFFFFu - anchor);
}

// ---------------- Kernel 1: threshold-collect (pure-ILP stream + dense tail) --
__global__ __launch_bounds__(256, 4) void collect_kernel(const float* __restrict__ pred,
                                                         unsigned long long* __restrict__ glist,
                                                         unsigned* __restrict__ gcnt) {
    __shared__ unsigned pend[512];
    __shared__ unsigned s_p;
    int b = blockIdx.y;
    int tid = threadIdx.x;
    unsigned stripe = (unsigned)blockIdx.x & (NSTRIPE - 1u);
    if (tid == 0) s_p = 0u;
    __syncthreads();
    const float4* p4 = (const float4*)(pred + (size_t)b * EL_PER_IMG);
    unsigned base4 = (unsigned)blockIdx.x * 2560u + (unsigned)tid;

    float4 v[10];
    unsigned fidx[10];
#pragma unroll
    for (int k = 0; k < 10; k++) {
        unsigned f = base4 + (unsigned)k * 256u;
        fidx[k] = f;
        unsigned fc = (f < (unsigned)F4_PER_IMG) ? f : (unsigned)(F4_PER_IMG - 1);
        v[k] = p4[fc];
    }
#pragma unroll
    for (int k = 0; k < 10; k++) {
        unsigned f = fidx[k];
        bool ok = (f < (unsigned)F4_PER_IMG) && (f % 21u != 0u);  // %21==0 => box cols
        float4 w = v[k];
        if (ok && (w.x >= XCUT || w.y >= XCUT || w.z >= XCUT || w.w >= XCUT)) {
#pragma unroll
            for (int j = 0; j < 4; j++) {
                float x = (j == 0) ? w.x : (j == 1) ? w.y : (j == 2) ? w.z : w.w;
                if (x >= XCUT) {
                    unsigned pos = atomicAdd(&s_p, 1u);
                    unsigned el = f * 4u + (unsigned)j;
                    if (pos < 512u) pend[pos] = el;
                    else emit_one(b, el, x, stripe, glist, gcnt);
                }
            }
        }
    }
    __syncthreads();
    unsigned np = s_p; if (np > 512u) np = 512u;
    for (unsigned i = (unsigned)tid; i < np; i += 256u) {
        unsigned el = pend[i];
        float x = pred[(size_t)b * EL_PER_IMG + el];
        emit_one(b, el, x, stripe, glist, gcnt);
    }
}

// parallel suffix (inclusive, from high index down) over 2048 u32 in LDS, 512 thr
__device__ __forceinline__ void suffix_scan_2048(unsigned* h, int tid) {
    for (unsigned off = 1; off < 2048; off <<= 1) {
        unsigned v[4];
#pragma unroll
        for (int q = 0; q < 4; q++) {
            unsigned t = (unsigned)tid + q * 512u;
            v[q] = (t + off < 2048u) ? h[t + off] : 0u;
        }
        __syncthreads();
#pragma unroll
        for (int q = 0; q < 4; q++) h[tid + q * 512] += v[q];
        __syncthreads();
    }
}

// ---------------- Kernel 2a: gather + partition + reg-bitonic + decode --------
__global__ __launch_bounds__(512) void select_decode_kernel(
        const float* __restrict__ pred, const unsigned long long* __restrict__ glist,
        const unsigned* __restrict__ gcnt,
        float4* __restrict__ g_xyxy, float4* __restrict__ g_xywh,
        float2* __restrict__ g_sa) {
    int bc = blockIdx.x;
    int b = bc / NCLS, c = bc - b * NCLS;
    int tid = threadIdx.x;

    __shared__ unsigned long long clist[2048];   // 16 KB raw gather / fallback scratch
    __shared__ unsigned long long sout[1024];    // 8 KB sorted output; fallback: fhist[2048] u32
    __shared__ unsigned eqbuf[1024];             // 4 KB: fast hist[512] / fallback eqlist[1024]
    __shared__ unsigned scnt[NSTRIPE], soff[NSTRIPE];
    __shared__ unsigned wsum[8];
    __shared__ int s_ok;
    __shared__ unsigned s_total, s_tb, a_ctr, e_ctr, s_fail;
    __shared__ unsigned sh_t, sh_above, s_cnt, s_eq;

    unsigned* hist = eqbuf;                      // 512 bins (fast path)

    const unsigned KCUT = mono_key(sigmoid_f(XCUT));
    const unsigned BASE = KCUT >> 12;            // fast keys in (KCUT, mono(1.0f)]

    if (tid < NSTRIPE)
        scnt[tid] = gcnt[(((unsigned)bc * NSTRIPE + (unsigned)tid) << 4)];
    for (int i = tid; i < 1024; i += 512) sout[i] = 0ull;
    if (tid < 512) hist[tid] = 0u;
    if (tid == 0) { a_ctr = 0u; e_ctr = 0u; s_fail = 0u; }
    __syncthreads();
    if (tid == 0) {
        unsigned o = 0; int ok = 1;
        for (int s = 0; s < NSTRIPE; s++) {
            unsigned cs_ = scnt[s];
            if (cs_ > SCAP) ok = 0;
            soff[s] = o;
            o += (cs_ < SCAP ? cs_ : SCAP);
        }
        s_total = o;
        s_ok = ok && (o >= PREK);
    }
    __syncthreads();

    // gather: 4 fully-independent vector loads per thread
#pragma unroll
    for (int q = 0; q < 4; q++) {
        unsigned qq = (unsigned)tid + (unsigned)q * 512u;       // < 2048 = 16*128
        unsigned s = qq >> 7, i = qq & (SCAP - 1u);
        unsigned long long e2 = glist[(size_t)((unsigned)bc * NSTRIPE + s) * SCAP + i];
        unsigned cs_ = scnt[s]; if (cs_ > SCAP) cs_ = SCAP;
        if (i < cs_) {
            clist[soff[s] + i] = e2;
            int bin = (int)((unsigned)(e2 >> 32) >> 12) - (int)BASE;
            bin = bin < 0 ? 0 : (bin > 511 ? 511 : bin);
            atomicAdd(&hist[bin], 1u);
        }
    }
    __syncthreads();

    bool fastb = (s_ok != 0);
    if (fastb) {
        unsigned vbin = hist[tid];
        int lane = tid & 63, w8 = tid >> 6;
#pragma unroll
        for (int off = 1; off < 64; off <<= 1) {
            unsigned u = (unsigned)__shfl_down((int)vbin, off, 64);
            if (lane + off < 64) vbin += u;
        }
        if (lane == 0) wsum[w8] = vbin;
        __syncthreads();
        if (tid == 0) {
            unsigned acc = 0;
            for (int w = 7; w >= 0; w--) { unsigned t = wsum[w]; wsum[w] = acc; acc += t; }
        }
        __syncthreads();
        vbin += wsum[w8];
        hist[tid] = vbin;          // suffix counts
        __syncthreads();
        unsigned S = vbin, S1 = (tid < 511) ? hist[tid + 1] : 0u;
        if (S >= PREK && S1 < PREK) s_tb = (unsigned)tid;
        __syncthreads();
        unsigned tb = s_tb;
        unsigned total = s_total;
        for (unsigned i = (unsigned)tid; i < total; i += 512u) {
            unsigned long long e2 = clist[i];
            int bin = (int)((unsigned)(e2 >> 32) >> 12) - (int)BASE;
            bin = bin < 0 ? 0 : (bin > 511 ? 511 : bin);
            if ((unsigned)bin > tb) {
                unsigned p = atomicAdd(&a_ctr, 1u);
                sout[p] = e2;
            } else if ((unsigned)bin == tb) {
                unsigned p = atomicAdd(&e_ctr, 1u);
                if (p < 512u) sout[512u + p] = e2;
                else s_fail = 1u;
            }
        }
        __syncthreads();
        if (s_fail) fastb = false;
    }
    if (fastb) {
        unsigned i0 = (unsigned)tid * 2u, i1 = i0 + 1u;
        unsigned long long v0 = sout[i0], v1 = sout[i1];
        for (unsigned k = 2; k <= 1024; k <<= 1) {
            for (unsigned j = k >> 1; j >= 1; j >>= 1) {
                if (j >= 128) {
                    sout[i0] = v0; sout[i1] = v1;
                    __syncthreads();
                    unsigned long long u0 = sout[i0 ^ j], u1 = sout[i1 ^ j];
                    v0 = ce_dir(v0, u0, i0, j, k);
                    v1 = ce_dir(v1, u1, i1, j, k);
                    __syncthreads();
                } else if (j >= 2) {
                    int d = (int)(j >> 1);
                    unsigned long long u0 = shflx64(v0, d), u1 = shflx64(v1, d);
                    v0 = ce_dir(v0, u0, i0, j, k);
                    v1 = ce_dir(v1, u1, i1, j, k);
                } else {
                    bool tm = ((i0 & k) == 0u);
                    unsigned long long mx = v0 > v1 ? v0 : v1;
                    unsigned long long mn = v0 > v1 ? v1 : v0;
                    v0 = tm ? mx : mn; v1 = tm ? mn : mx;
                }
            }
        }
        sout[i0] = v0; sout[i1] = v1;
        __syncthreads();
        unsigned key511 = (unsigned)(sout[511] >> 32);
        fastb = key511 > KCUT;     // proof: every uncollected key <= KCUT
    }

    if (!fastb) {
        // exact 3-level radix-select fallback (never taken on bench input)
        unsigned* fhist = (unsigned*)sout;       // 2048 u32
        unsigned* eqlist = eqbuf;                // 1024 u32
        const float* predc = pred + (size_t)b * NANCH * 84 + 4 + c;
        auto getkey = [&](int i) -> unsigned {
            return mono_key(sigmoid_f(predc[(size_t)i * 84]));
        };
        __syncthreads();
        for (int t = tid; t < 2048; t += 512) fhist[t] = 0u;
        __syncthreads();
        for (int i = tid; i < NANCH; i += 512) atomicAdd(&fhist[getkey(i) >> 21], 1u);
        __syncthreads();
        suffix_scan_2048(fhist, tid);
        unsigned target = PREK;
#pragma unroll
        for (int q = 0; q < 4; q++) {
            int t = tid + q * 512;
            unsigned St = fhist[t], St1 = (t < 2047) ? fhist[t + 1] : 0u;
            if (St >= target && St1 < target) { sh_t = (unsigned)t; sh_above = St1; }
        }
        __syncthreads();
        unsigned t0 = sh_t, above = sh_above;
        __syncthreads();
        for (int t = tid; t < 2048; t += 512) fhist[t] = 0u;
        __syncthreads();
        for (int i = tid; i < NANCH; i += 512) {
            unsigned k = getkey(i);
            if ((k >> 21) == t0) atomicAdd(&fhist[(k >> 10) & 0x7FFu], 1u);
        }
        __syncthreads();
        suffix_scan_2048(fhist, tid);
        target = PREK - above;
#pragma unroll
        for (int q = 0; q < 4; q++) {
            int t = tid + q * 512;
            unsigned St = fhist[t], St1 = (t < 2047) ? fhist[t + 1] : 0u;
            if (St >= target && St1 < target) { sh_t = (unsigned)t; sh_above = St1; }
        }
        __syncthreads();
        unsigned t1 = sh_t; above += sh_above;
        __syncthreads();
        for (int t = tid; t < 2048; t += 512) fhist[t] = 0u;
        __syncthreads();
        unsigned pfx2 = (t0 << 11) | t1;
        for (int i = tid; i < NANCH; i += 512) {
            unsigned k = getkey(i);
            if ((k >> 10) == pfx2) atomicAdd(&fhist[k & 0x3FFu], 1u);
        }
        __syncthreads();
        suffix_scan_2048(fhist, tid);
        target = PREK - above;
#pragma unroll
        for (int q = 0; q < 4; q++) {
            int t = tid + q * 512;
            unsigned St = fhist[t], St1 = (t < 2047) ? fhist[t + 1] : 0u;
            if (St >= target && St1 < target) { sh_t = (unsigned)t; sh_above = St1; }
        }
        __syncthreads();
        unsigned t2 = sh_t; above += sh_above;
        unsigned B = (t0 << 21) | (t1 << 10) | t2;
        unsigned R = PREK - above;
        if (tid == 0) { s_cnt = 0u; s_eq = 0u; }
        __syncthreads();
        for (int i = tid; i < NANCH; i += 512) {
            unsigned k = getkey(i);
            if (k > B) {
                unsigned p = atomicAdd(&s_cnt, 1u);
                clist[p] = ((unsigned long long)k << 32) | (unsigned long long)(0xFFFFFFFFu - (unsigned)i);
            } else if (k == B) {
                unsigned p = atomicAdd(&s_eq, 1u);
                if (p < 1024u) eqlist[p] = (unsigned)i;
            }
        }
        __syncthreads();
        unsigned eqn = s_eq < 1024u ? s_eq : 1024u;
        for (int t = tid; t < 1024; t += 512)
            if ((unsigned)t >= eqn) eqlist[t] = 0xFFFFFFFFu;
        __syncthreads();
        for (unsigned k2 = 2; k2 <= 1024; k2 <<= 1)
            for (unsigned j = k2 >> 1; j > 0; j >>= 1) {
                for (int i = tid; i < 1024; i += 512) {
                    unsigned ixj = (unsigned)i ^ j;
                    if (ixj > (unsigned)i) {
                        unsigned a = eqlist[i], bb = eqlist[ixj];
                        bool asc = (((unsigned)i & k2) == 0u);
                        if (asc ? (a > bb) : (a < bb)) { eqlist[i] = bb; eqlist[ixj] = a; }
                    }
                }
                __syncthreads();
            }
        for (unsigned t = tid; t < R; t += 512) {
            unsigned idxe = eqlist[t];
            clist[above + t] = ((unsigned long long)B << 32) | (unsigned long long)(0xFFFFFFFFu - idxe);
        }
        __syncthreads();
        for (unsigned k2 = 2; k2 <= PREK; k2 <<= 1)
            for (unsigned j = k2 >> 1; j > 0; j >>= 1) {
                unsigned i = (unsigned)tid, ixj = i ^ j;
                if (ixj > i) {
                    unsigned long long a = clist[i], bb = clist[ixj];
                    bool desc = ((i & k2) == 0u);
                    if (desc ? (a < bb) : (a > bb)) { clist[i] = bb; clist[ixj] = a; }
                }
                __syncthreads();
            }
        __syncthreads();
    }

    // ---- decode the 512 sorted candidates -> global (exact reference math) ----
    unsigned long long e = fastb ? sout[tid] : clist[tid];
    unsigned key = (unsigned)(e >> 32);
    unsigned aidx = 0xFFFFFFFFu - (unsigned)(e & 0xFFFFFFFFull);
    float score = mono_val(key);
    const float4 pv = *(const float4*)(pred + ((size_t)b * NANCH + aidx) * 84);
    float ax, ay, aw, ah;
    anchor_at((int)aidx, ax, ay, aw, ah);
    float bx = pv.x * 0.1f, by = pv.y * 0.1f, bw2 = pv.z * 0.2f, bh2 = pv.w * 0.2f;
    float cx = bx * aw + ax, cy = by * ah + ay;
    float w = (float)exp((double)bw2) * aw;
    float h = (float)exp((double)bh2) * ah;
    float x1 = cx - w * 0.5f, y1 = cy - h * 0.5f;
    float x2 = cx + w * 0.5f, y2 = cy + h * 0.5f;
    float area = (x2 - x1) * (y2 - y1);
    size_t gi = (size_t)bc * PREK + (unsigned)tid;
    g_xyxy[gi] = make_float4(x1, y1, x2, y2);
    g_xywh[gi] = make_float4(cx, cy, w, h);
    g_sa[gi]   = make_float2(score, area);
}

// ---------------- Kernel 2b: ADAPTIVE chunked bitmask NMS ---------------------
__global__ __launch_bounds__(512) void nms_kernel(
        const float4* __restrict__ g_xyxy, const float4* __restrict__ g_xywh,
        const float2* __restrict__ g_sa,
        float* __restrict__ cls_scores, float* __restrict__ cls_boxes) {
    int bc = blockIdx.x;
    int tid = threadIdx.x;

    __shared__ unsigned rowb[512 * 17];      // 34.8 KB bit rows (17-stride)
    __shared__ float4 sbox[PREK];            // 8 KB
    __shared__ float sarea[PREK];            // 2 KB
    __shared__ int svalid[PREK];             // 2 KB
    __shared__ unsigned keepw[16];
    __shared__ unsigned svalw[16];
    __shared__ unsigned wsum[8];
    __shared__ unsigned s_kept;

    size_t gi = (size_t)bc * PREK + (unsigned)tid;
    float4 bx4 = g_xyxy[gi];
    float4 xywh = g_xywh[gi];
    float2 sa = g_sa[gi];
    float score = sa.x, area = sa.y;
    int validr = (score > CONF_THRF) ? 1 : 0;
    sbox[tid] = bx4;
    sarea[tid] = area;
    svalid[tid] = validr;
    for (int i = tid; i < 512 * 17; i += 512) rowb[i] = 0u;   // unbuilt cols read as 0
    int w_ = tid >> 6, lane6 = tid & 63;
    unsigned long long vbal = __ballot(validr != 0);
    if (lane6 == 0) {
        svalw[2 * w_] = (unsigned)vbal;
        svalw[2 * w_ + 1] = (unsigned)(vbal >> 32);
    }
    if (tid < 16) keepw[tid] = 0xFFFFFFFFu;
    if (tid == 0) s_kept = 0u;
    __syncthreads();

    for (int c = 0; c < 4; c++) {
        int ntiles = 4 * c + 3;
        for (int p = w_; p < ntiles; p += 8) {
            int fct = 2 * c + 1;
            int ct = (p < fct) ? 2 * c : 2 * c + 1;
            int rt = (p < fct) ? p : p - fct;
            int r = rt * 64 + lane6;
            float4 br = sbox[r];
            float ar = sarea[r];
            int vr = svalid[r];
            unsigned m0 = 0u, m1 = 0u;
#pragma unroll 8
            for (int jj = 0; jj < 64; jj++) {
                int j = ct * 64 + jj;
                float4 bj = sbox[j];
                float aj = sarea[j];
                float xx1 = fmaxf(br.x, bj.x);
                float yy1 = fmaxf(br.y, bj.y);
                float xx2 = fminf(br.z, bj.z);
                float yy2 = fminf(br.w, bj.w);
                float ww = fmaxf(xx2 - xx1, 0.0f);
                float hh = fmaxf(yy2 - yy1, 0.0f);
                float inter = ww * hh;
                float uni = ar + aj - inter;
                float iou = inter / fmaxf(uni, 1e-8f);   // exact reference arithmetic
                bool sup = (iou > IOU_THRF) && (j > r) && vr;
                if (jj < 32) m0 |= sup ? (1u << jj) : 0u;
                else         m1 |= sup ? (1u << (jj - 32)) : 0u;
            }
            rowb[r * 17 + 2 * ct] = m0;
            rowb[r * 17 + 2 * ct + 1] = m1;
        }
        __syncthreads();

        if (tid < 64) {
            int w16 = tid & 15;
            unsigned kw = keepw[w16];
            if (c > 0) {
                unsigned a0 = 0u, a1 = 0u, a2 = 0u, a3 = 0u;
                for (int i = tid; i < 128 * c; i += 64) {
                    bool ki = (keepw[i >> 5] >> (i & 31)) & 1u;
                    if (ki) {
                        a0 |= rowb[i * 17 + 4 * c + 0];
                        a1 |= rowb[i * 17 + 4 * c + 1];
                        a2 |= rowb[i * 17 + 4 * c + 2];
                        a3 |= rowb[i * 17 + 4 * c + 3];
                    }
                }
#pragma unroll
                for (int d = 1; d < 64; d <<= 1) {
                    a0 |= (unsigned)__shfl_xor((int)a0, d, 64);
                    a1 |= (unsigned)__shfl_xor((int)a1, d, 64);
                    a2 |= (unsigned)__shfl_xor((int)a2, d, 64);
                    a3 |= (unsigned)__shfl_xor((int)a3, d, 64);
                }
                if (w16 == 4 * c + 0) kw &= ~a0;
                if (w16 == 4 * c + 1) kw &= ~a1;
                if (w16 == 4 * c + 2) kw &= ~a2;
                if (w16 == 4 * c + 3) kw &= ~a3;
            }
            for (int cch = 4 * c; cch < 4 * c + 4; cch++) {
                unsigned local = (unsigned)__shfl((int)kw, cch);
                for (int ii = 0; ii < 32; ii++) {
                    int i = cch * 32 + ii;
                    unsigned rb = rowb[i * 17 + w16];
                    unsigned rloc = rowb[i * 17 + cch];
                    if ((local >> ii) & 1u) {
                        local &= ~rloc;
                        kw &= ~rb;
                    }
                }
            }
            if (tid < 16) keepw[w16] = kw;
            unsigned cntv = (tid < 16 && w16 < 4 * (c + 1))
                          ? (unsigned)__popc(kw & svalw[w16]) : 0u;
#pragma unroll
            for (int d = 1; d < 64; d <<= 1) cntv += (unsigned)__shfl_xor((int)cntv, d, 64);
            if (tid == 0) s_kept = cntv;
        }
        __syncthreads();
        if (s_kept >= MAXDET) break;
    }

    unsigned kbit = (keepw[tid >> 5] >> (tid & 31)) & 1u;
    int kept = (int)kbit & validr;
    unsigned long long bal = __ballot(kept != 0);
    if (lane6 == 0) wsum[w_] = (unsigned)__popcll(bal);
    __syncthreads();
    int rank = 0;
    for (int u = 0; u < w_; u++) rank += (int)wsum[u];
    rank += (int)__popcll(bal & ((1ull << lane6) - 1ull));

    float* cs = cls_scores + (size_t)bc * MAXDET;
    float* cb = cls_boxes + (size_t)bc * MAXDET * 4;
    for (int r = tid; r < MAXDET; r += 512) {
        cs[r] = -1.0f;
        cb[r * 4 + 0] = -1.0f; cb[r * 4 + 1] = -1.0f;
        cb[r * 4 + 2] = -1.0f; cb[r * 4 + 3] = -1.0f;
    }
    __syncthreads();
    if (kept && rank < MAXDET) {
        cs[rank] = score;
        cb[rank * 4 + 0] = xywh.x; cb[rank * 4 + 1] = xywh.y;
        cb[rank * 4 + 2] = xywh.z; cb[rank * 4 + 3] = xywh.w;
    }
}

// ---------------- Kernel 3: per-image top-100 via radix select ----------------
// r6's 8192 bitonic sort was DS-pipe-bound (77 us, 0.7% VALU): ~40 shfl stages
// x 16 bpermutes/thread serialized on the LDS pipe of 4 CUs. Replace with:
// 4-pass 8-bit radix select for the 100th-largest key (exact), tie-break by
// 2-pass ascending radix select on flat index (exact for any multiplicity),
// then a single-wave 128-element bitonic for output ordering.
__global__ __launch_bounds__(1024) void final_topk(const float* __restrict__ cls_scores,
                                                   const float* __restrict__ cls_boxes,
                                                   float* __restrict__ out) {
    int b = blockIdx.x;
    int tid = threadIdx.x;
    __shared__ unsigned hist[256];
    __shared__ unsigned wpart[4];
    __shared__ unsigned long long win[128];
    __shared__ unsigned long long balw[16];
    __shared__ unsigned s_prefix, s_need, s_bin, s_above, s_istar, w_ctr;

    unsigned idx0 = (unsigned)tid * 8u;
    unsigned rk[8];
#pragma unroll
    for (int e = 0; e < 8; e++) {
        unsigned i = idx0 + (unsigned)e;
        rk[e] = (i < (unsigned)(NCLS * MAXDET))
              ? mono_key(cls_scores[(size_t)b * NCLS * MAXDET + i]) : 0u;
        // note: mono_key of any real float > 0, so pads (key 0) are never selected
    }
    if (tid == 0) { s_prefix = 0u; s_need = MAXDET; }
    __syncthreads();

    // ---- 4-pass descending radix select: K = 100th-largest key ----
    for (int pass = 0; pass < 4; pass++) {
        int shift = 24 - 8 * pass;
        if (tid < 256) hist[tid] = 0u;
        __syncthreads();
        unsigned pfx = s_prefix;
#pragma unroll
        for (int e = 0; e < 8; e++) {
            unsigned k = rk[e];
            if (pass == 0 || (k >> (shift + 8)) == pfx)
                atomicAdd(&hist[(k >> shift) & 0xFFu], 1u);
        }
        __syncthreads();
        unsigned v = 0u;
        if (tid < 256) {
            v = hist[tid];
            int lane = tid & 63;
#pragma unroll
            for (int off = 1; off < 64; off <<= 1) {
                unsigned u = (unsigned)__shfl_down((int)v, off, 64);
                if (lane + off < 64) v += u;
            }
            if (lane == 0) wpart[tid >> 6] = v;
        }
        __syncthreads();
        if (tid == 0) {
            unsigned acc = 0;
            for (int w = 3; w >= 0; w--) { unsigned t = wpart[w]; wpart[w] = acc; acc += t; }
        }
        __syncthreads();
        if (tid < 256) { v += wpart[tid >> 6]; hist[tid] = v; }   // inclusive suffix count
        __syncthreads();
        unsigned nd = s_need;
        if (tid < 256) {
            unsigned S = hist[tid], S1 = (tid < 255) ? hist[tid + 1] : 0u;
            if (S >= nd && S1 < nd) { s_bin = (unsigned)tid; s_above = S1; }
        }
        __syncthreads();
        if (tid == 0) { s_prefix = (s_prefix << 8) | s_bin; s_need = s_need - s_above; }
        __syncthreads();
    }
    unsigned K = s_prefix;       // exact 100th-largest key
    unsigned R = s_need;         // how many key==K entries to take (by flat index asc), >=1

    // ---- ascending radix select on flat index among key==K: I* = R-th smallest ----
    if (tid < 256) hist[tid] = 0u;
    __syncthreads();
#pragma unroll
    for (int e = 0; e < 8; e++) {
        unsigned i = idx0 + (unsigned)e;
        if (rk[e] == K) atomicAdd(&hist[i >> 5], 1u);    // 256 bins of 32 indices
    }
    __syncthreads();
    unsigned v2 = 0u;
    if (tid < 256) {
        v2 = hist[tid];
        int lane = tid & 63;
#pragma unroll
        for (int off = 1; off < 64; off <<= 1) {
            unsigned u = (unsigned)__shfl_up((int)v2, off, 64);
            if (lane >= off) v2 += u;
        }
        if (lane == 63) wpart[tid >> 6] = v2;
    }
    __syncthreads();
    if (tid == 0) {
        unsigned acc = 0;
        for (int w = 0; w < 4; w++) { unsigned t = wpart[w]; wpart[w] = acc; acc += t; }
    }
    __syncthreads();
    if (tid < 256) { v2 += wpart[tid >> 6]; hist[tid] = v2; }     // inclusive ascending cum
    __syncthreads();
    if (tid < 256) {
        unsigned C = hist[tid], C0 = (tid > 0) ? hist[tid - 1] : 0u;
        if (C >= R && C0 < R) { s_bin = (unsigned)tid; s_above = R - C0; }   // s_above := Rrem
    }
    __syncthreads();
    unsigned tA = s_bin, Rrem = s_above;
    if (tid < 32) hist[tid] = 0u;
    __syncthreads();
#pragma unroll
    for (int e = 0; e < 8; e++) {
        unsigned i = idx0 + (unsigned)e;
        if (rk[e] == K && (i >> 5) == tA) atomicAdd(&hist[i & 31u], 1u);
    }
    __syncthreads();
    if (tid < 32) {
        unsigned vv = hist[tid];
        unsigned own = vv;
#pragma unroll
        for (int off = 1; off < 32; off <<= 1) {
            unsigned u = (unsigned)__shfl_up((int)vv, off, 64);
            if (tid >= off) vv += u;
        }
        unsigned C0 = vv - own;
        if (vv >= Rrem && C0 < Rrem) s_istar = (tA << 5) | (unsigned)tid;
    }
    if (tid == 0) w_ctr = 0u;
    __syncthreads();
    unsigned Istar = s_istar;    // flat indices are unique -> count(idx<=I*, ==K) == R

    // ---- gather exactly 100 winners ----
#pragma unroll
    for (int e = 0; e < 8; e++) {
        unsigned i = idx0 + (unsigned)e;
        unsigned k = rk[e];
        if (k > K || (k == K && i <= Istar)) {
            unsigned p = atomicAdd(&w_ctr, 1u);
            if (p < 128u)
                win[p] = ((unsigned long long)k << 32)
                       | (unsigned long long)(0xFFFFFFFFu - i);
        }
    }
    __syncthreads();
    if (tid >= (int)w_ctr && tid < 128) win[tid] = 0ull;
    __syncthreads();

    // ---- single-wave bitonic sort of 128 winners (desc key, asc index) ----
    if (tid < 64) {
        unsigned i0 = (unsigned)tid * 2u, i1 = i0 + 1u;
        unsigned long long v0 = win[i0], v1 = win[i1];
        for (unsigned k2 = 2; k2 <= 128; k2 <<= 1) {
            for (unsigned j = k2 >> 1; j >= 1; j >>= 1) {
                if (j >= 2) {
                    int d = (int)(j >> 1);
                    unsigned long long u0 = shflx64(v0, d), u1 = shflx64(v1, d);
                    v0 = ce_dir(v0, u0, i0, j, k2);
                    v1 = ce_dir(v1, u1, i1, j, k2);
                } else {
                    bool tm = ((i0 & k2) == 0u);
                    unsigned long long mx = v0 > v1 ? v0 : v1;
                    unsigned long long mn = v0 > v1 ? v1 : v0;
                    v0 = tm ? mx : mn; v1 = tm ? mn : mx;
                }
            }
        }
        win[i0] = v0; win[i1] = v1;
    }
    __syncthreads();

    // ---- outputs ----
    bool vd = false;
    if (tid < MAXDET) {
        unsigned long long e = win[tid];
        unsigned mk = (unsigned)(e >> 32);
        float s = mono_val(mk);
        unsigned fi = 0xFFFFFFFFu - (unsigned)(e & 0xFFFFFFFFull);
        vd = (s >= CONF_THRF);
        float obx = -1.0f, oby = -1.0f, obw = -1.0f, obh = -1.0f;
        float ofs = -1.0f, ofc = -1.0f;
        if (vd) {
            const float* bp = cls_boxes + ((size_t)b * NCLS * MAXDET + fi) * 4;
            obx = bp[0]; oby = bp[1]; obw = bp[2]; obh = bp[3];
            ofs = s;
            ofc = (float)(fi / MAXDET);
        }
        int o = b * MAXDET + tid;
        out[o * 4 + 0] = obx; out[o * 4 + 1] = oby;
        out[o * 4 + 2] = obw; out[o * 4 + 3] = obh;
        out[NIMG * MAXDET * 4 + o] = ofs;
        out[NIMG * MAXDET * 5 + o] = ofc;
    }
    unsigned long long bal = __ballot(vd);
    if ((tid & 63) == 0) balw[tid >> 6] = bal;
    __syncthreads();
    if (tid == 0) {
        int cnt2 = 0;
        for (int u = 0; u < 16; u++) cnt2 += (int)__popcll(balw[u]);
        out[NIMG * MAXDET * 6 + b] = (float)cnt2;
    }
}

extern "C" void kernel_launch(void* const* d_in, const int* in_sizes, int n_in,
                              void* d_out, int out_size, void* d_ws, size_t ws_size,
                              hipStream_t stream) {
    (void)in_sizes; (void)n_in; (void)out_size; (void)ws_size;
    const float* pred = (const float*)d_in[1];  // d_in[0] = images (only H=W=640 used)
    float* out = (float*)d_out;

    char* base = (char*)d_ws;
    size_t off = 0;
    unsigned* gcnt = (unsigned*)(base + off);                  // 5120 x 64B = 327,680
    off += (size_t)NSUB * 16 * sizeof(unsigned);
    unsigned long long* glist = (unsigned long long*)(base + off);  // 5.24 MB
    off += (size_t)NSUB * SCAP * 8u;
    float4* g_xyxy = (float4*)(base + off);                    // 2.62 MB
    off += (size_t)NBC * PREK * 16u;
    float4* g_xywh = (float4*)(base + off);                    // 2.62 MB
    off += (size_t)NBC * PREK * 16u;
    float2* g_sa = (float2*)(base + off);                      // 1.31 MB
    off += (size_t)NBC * PREK * 8u;
    float* cls_scores = (float*)(base + off);                  // 128 KB
    off += (size_t)NBC * MAXDET * sizeof(float);
    float* cls_boxes = (float*)(base + off);                   // 512 KB

    hipMemsetAsync(gcnt, 0, (size_t)NSUB * 16 * sizeof(unsigned), stream);
    collect_kernel<<<dim3(630, NIMG), 256, 0, stream>>>(pred, glist, gcnt);
    select_decode_kernel<<<NBC, 512, 0, stream>>>(pred, glist, gcnt, g_xyxy, g_xywh, g_sa);
    nms_kernel<<<NBC, 512, 0, stream>>>(g_xyxy, g_xywh, g_sa, cls_scores, cls_boxes);
    final_topk<<<NIMG, 1024, 0, stream>>>(cls_scores, cls_boxes, out);
}